// Round 11
// baseline (894.217 us; speedup 1.0000x reference)
//
#include <hip/hip_runtime.h>
#include <math.h>

#define NV 20000
#define NE 100000
#define DD 32
#define NG 1000
#define NDEPTH 3
#define S2S 6
#define NBK 8    // src-nodes per block in k_fused
#define EPB 16   // edges per block in k_edge_t3
#define CAPN 128 // max nodes of one graph staged in LDS
#define SCAN_T 256
#define SCAN_C 80  // 256*80 = 20480 >= NV

__device__ __forceinline__ float sigmoidf_(float x) { return 1.0f / (1.0f + __expf(-x)); }

// ---------------- prolog: embed_node | embed_edge | graph bounds | deg zero ----------------
__global__ void k_prolog(const float* __restrict__ node, const float* __restrict__ Wn,
                         const float* __restrict__ bn, float* __restrict__ h,
                         float* __restrict__ h0,
                         const float* __restrict__ edge, const float* __restrict__ We,
                         const float* __restrict__ be, float* __restrict__ e_h,
                         const int* __restrict__ n2g, int* __restrict__ gstart,
                         int* __restrict__ deg) {
    __shared__ float sWn[36 * DD];
    __shared__ float sbn[DD];
    __shared__ float sxn[32][36];
    __shared__ float sWe[12 * DD];
    __shared__ float sbe[DD];
    __shared__ float sxe[32][12];
    int tid = threadIdx.x;
    int b = blockIdx.x;
    if (b < 625) {
        for (int i = tid; i < 36 * DD; i += 256) sWn[i] = Wn[i];
        if (tid < DD) sbn[tid] = bn[tid];
        int v0 = b * 32;
        for (int i = tid; i < 32 * 36; i += 256) sxn[i / 36][i % 36] = node[(size_t)v0 * 36 + i];
        __syncthreads();
        int f = tid & 31;
        int nb = tid >> 5;
        for (int g = 0; g < 4; ++g) {
            int n = nb + 8 * g;
            float acc = sbn[f];
            #pragma unroll
            for (int i = 0; i < 36; ++i) acc += sxn[n][i] * sWn[i * DD + f];
            float y = acc > 0.f ? acc : 0.01f * acc;
            h[(size_t)(v0 + n) * DD + f] = y;
            h0[(size_t)(v0 + n) * DD + f] = y;
        }
    } else if (b < 3750) {
        for (int i = tid; i < 12 * DD; i += 256) sWe[i] = We[i];
        if (tid < DD) sbe[tid] = be[tid];
        int e0 = (b - 625) * 32;
        for (int i = tid; i < 32 * 12; i += 256) sxe[i / 12][i % 12] = edge[(size_t)e0 * 12 + i];
        __syncthreads();
        int f = tid & 31;
        int nb = tid >> 5;
        for (int g = 0; g < 4; ++g) {
            int n = nb + 8 * g;
            float acc = sbe[f];
            #pragma unroll
            for (int i = 0; i < 12; ++i) acc += sxe[n][i] * sWe[i * DD + f];
            float y = acc > 0.f ? acc : 0.01f * acc;
            e_h[(size_t)(e0 + n) * DD + f] = y;
        }
    } else if (b < 3755) {
        int g = (b - 3750) * 256 + tid;
        if (g <= NG) {
            int lo = 0, hi = NV;
            while (lo < hi) {
                int mid = (lo + hi) >> 1;
                if (n2g[mid] < g) lo = mid + 1; else hi = mid;
            }
            gstart[g] = lo;
        }
    } else {
        int i = (b - 3755) * 256 + tid;
        if (i < NV) deg[i] = 0;
    }
}

// ---------------- CSR build ----------------
__global__ void k_hist(const int* __restrict__ src, int* __restrict__ deg) {
    int e = blockIdx.x * blockDim.x + threadIdx.x;
    if (e < NE) atomicAdd(&deg[src[e]], 1);
}

__global__ void k_scan(const int* __restrict__ deg, int* __restrict__ estart, int* __restrict__ cur) {
    __shared__ int sdeg[SCAN_T * SCAN_C];
    __shared__ int spart[SCAN_T];
    int tid = threadIdx.x;
    for (int i = tid; i < SCAN_T * SCAN_C; i += SCAN_T) sdeg[i] = (i < NV) ? deg[i] : 0;
    __syncthreads();
    int base = tid * SCAN_C;
    int sum = 0;
    for (int j = 0; j < SCAN_C; ++j) sum += sdeg[base + j];
    spart[tid] = sum;
    __syncthreads();
    for (int off = 1; off < SCAN_T; off <<= 1) {
        int v = (tid >= off) ? spart[tid - off] : 0;
        __syncthreads();
        spart[tid] += v;
        __syncthreads();
    }
    int run = spart[tid] - sum;
    for (int j = 0; j < SCAN_C; ++j) {
        int idx = base + j;
        if (idx < NV) { estart[idx] = run; cur[idx] = run; }
        run += sdeg[base + j];
    }
    if (tid == SCAN_T - 1) estart[NV] = run;
}

__global__ void k_scatter(const int* __restrict__ src, int* __restrict__ cur,
                          int* __restrict__ esorted) {
    int e = blockIdx.x * blockDim.x + threadIdx.x;
    if (e < NE) {
        int s = src[e];
        int pos = atomicAdd(&cur[s], 1);
        esorted[pos] = e;
    }
}

// ---------------- all-layer edge hidden: t[l] = relu(e_h @ eW1[l] + eb1[l]) ----------------
__global__ void k_edge_t3(const float* __restrict__ e_h, const float* __restrict__ eW1,
                          const float* __restrict__ eb1, float* __restrict__ t3,
                          float* __restrict__ agg) {
    __shared__ float sW[DD * 64];
    __shared__ float sb[64];
    int tid = threadIdx.x;
    int b = blockIdx.x;
    if (b < (NV * DD) / 256) agg[(size_t)b * 256 + tid] = 0.f;
    int l = b / 6250, bb = b % 6250;
    const float* W = eW1 + (size_t)l * DD * 64;
    float* t = t3 + (size_t)l * NE * 64;
    for (int i = tid; i < DD * 64; i += 256) sW[i] = W[i];
    if (tid < 64) sb[tid] = eb1[l * 64 + tid];
    int e0 = bb * EPB;
    __syncthreads();
    int k = tid & 63;
    int nb = tid >> 6;
    float acc[4];
    #pragma unroll
    for (int g = 0; g < 4; ++g) acc[g] = sb[k];
    #pragma unroll
    for (int d4 = 0; d4 < 8; ++d4) {
        float4 ex[4];
        #pragma unroll
        for (int g = 0; g < 4; ++g)
            ex[g] = *(const float4*)(e_h + (size_t)(e0 + nb + 4 * g) * DD + d4 * 4);
        #pragma unroll
        for (int dd = 0; dd < 4; ++dd) {
            float w = sW[(d4 * 4 + dd) * 64 + k];
            #pragma unroll
            for (int g = 0; g < 4; ++g)
                acc[g] = fmaf((&ex[g].x)[dd], w, acc[g]);
        }
    }
    #pragma unroll
    for (int g = 0; g < 4; ++g)
        t[(size_t)(e0 + nb + 4 * g) * 64 + k] = fmaxf(acc[g], 0.f);
}

// ---------------- fused: per-tile A in LDS + per-node A-in-registers edge phase ----------------
// Phase-1: h via wave-uniform float4 loads (no readlane). Phase-2: t broadcast via per-wave
// LDS row + 8x ds_read_b128 (uniform per half-wave -> broadcast), k-contiguous Areg.
__global__ __launch_bounds__(1024, 8) void k_fused(const float* __restrict__ h,
        const float* __restrict__ eW2, const float* __restrict__ eb2,
        const float* __restrict__ t, const int* __restrict__ dst,
        const int* __restrict__ estart, const int* __restrict__ esorted,
        float* __restrict__ agg) {
    int v0 = blockIdx.x * NBK;
    __shared__ float sA[NBK][64][32];   // 64 KB, [n][k][f]
    __shared__ float sbb[NBK][32];
    __shared__ __align__(16) float tbuf[16][64];   // per-wave t-row scratch
    int tid = threadIdx.x;
    int lane = tid & 63;

    int f = tid & 31;
    int kb = tid >> 5;                  // 0..31
    const float* wbase = eW2 + kb * 1024 + f;

    float acc[2][8];
    #pragma unroll
    for (int jj = 0; jj < 2; ++jj)
        #pragma unroll
        for (int n = 0; n < 8; ++n) acc[jj][n] = 0.f;

    #pragma unroll
    for (int d4 = 0; d4 < 8; ++d4) {
        // wave-uniform h loads (address independent of threadIdx -> scalarizable)
        float4 hv[8];
        #pragma unroll
        for (int n = 0; n < 8; ++n)
            hv[n] = *(const float4*)(h + (size_t)(v0 + n) * DD + d4 * 4);
        #pragma unroll
        for (int jj = 0; jj < 2; ++jj) {
            const float* wp = wbase + jj * 32 * 1024 + d4 * 128;
            #pragma unroll
            for (int dd = 0; dd < 4; ++dd) {
                float w = wp[dd * 32];
                #pragma unroll
                for (int n = 0; n < 8; ++n)
                    acc[jj][n] = fmaf((&hv[n].x)[dd], w, acc[jj][n]);
            }
        }
    }
    #pragma unroll
    for (int jj = 0; jj < 2; ++jj)
        #pragma unroll
        for (int n = 0; n < 8; ++n)
            sA[n][kb + 32 * jj][f] = acc[jj][n];

    if (tid < 256) {
        int n = tid >> 5;
        float bacc = 0.f;
        #pragma unroll
        for (int d = 0; d < DD; ++d)
            bacc = fmaf(h[(size_t)(v0 + n) * DD + d], eb2[d * 32 + f], bacc);
        sbb[n][f] = bacc;
    }
    __syncthreads();

    // edge phase: wave w -> node w>>1, edge parity w&1.
    // lane (f,hf) accumulates k in [32*hf, 32*hf+32); t-row staged in tbuf[w].
    int w = tid >> 6;
    int n = w >> 1;
    int par = w & 1;
    int hf = lane >> 5;
    float Areg[32];
    #pragma unroll
    for (int q = 0; q < 32; ++q)
        Areg[q] = sA[n][32 * hf + q][f];   // 2 lanes/bank, different addr: free
    float bbv = sbb[n][f];
    float* tb = &tbuf[w][0];
    int i = estart[v0 + n] + par, e1 = estart[v0 + n + 1];
    if (i < e1) {
        int e = esorted[i];
        float tv = t[(size_t)e * 64 + lane];
        int dn = dst[e];
        while (i < e1) {
            i += 2;
            float tv2 = 0.f; int dn2 = 0;
            if (i < e1) {
                int e2 = esorted[i];
                tv2 = t[(size_t)e2 * 64 + lane];
                dn2 = dst[e2];
            }
            tb[lane] = tv;                         // ds_write_b32 (wave-synchronous)
            const float4* tq4 = (const float4*)(tb + 32 * hf);
            float m0 = 0.f, m1 = 0.f, m2 = 0.f, m3 = 0.f;
            #pragma unroll
            for (int q4 = 0; q4 < 8; ++q4) {
                float4 tq = tq4[q4];               // uniform per half-wave -> broadcast
                m0 = fmaf(tq.x, Areg[4 * q4 + 0], m0);
                m1 = fmaf(tq.y, Areg[4 * q4 + 1], m1);
                m2 = fmaf(tq.z, Areg[4 * q4 + 2], m2);
                m3 = fmaf(tq.w, Areg[4 * q4 + 3], m3);
            }
            float m = (m0 + m1) + (m2 + m3);
            m += __shfl_xor(m, 32, 64);
            if (lane < 32) atomicAdd(&agg[(size_t)dn * DD + f], m + bbv);
            tv = tv2; dn = dn2;
        }
    }
}

// ---------------- GRU + LayerNorm (8 nodes/block); re-zeroes agg for next layer ----------------
__global__ __launch_bounds__(256, 2) void k_gru_ln(float* __restrict__ agg,
                         const float* __restrict__ h0,
                         const float* __restrict__ wih, const float* __restrict__ whh,
                         const float* __restrict__ bih, const float* __restrict__ bhh,
                         const float* __restrict__ lng, const float* __restrict__ lnb,
                         float* __restrict__ h) {
    __shared__ float sWT[2][3][32][33];   // [ih/hh][gate][f][j], j-dim padded
    __shared__ float sbih[96], sbhh[96], sg[DD], sb[DD];
    int tid = threadIdx.x;
    for (int i = tid; i < 3072; i += 256) {
        int g = i >> 10, j = (i >> 5) & 31, f = i & 31;
        sWT[0][g][f][j] = wih[i];
        sWT[1][g][f][j] = whh[i];
    }
    if (tid < 96) { sbih[tid] = bih[tid]; sbhh[tid] = bhh[tid]; }
    if (tid < DD) { sg[tid] = lng[tid]; sb[tid] = lnb[tid]; }
    int v0 = blockIdx.x * 8;
    __syncthreads();
    int j = tid & 31;
    int n = v0 + (tid >> 5);
    float4 aq[8], hq[8];
    #pragma unroll
    for (int f4 = 0; f4 < 8; ++f4) {
        float4 a = *(const float4*)(agg + (size_t)n * DD + f4 * 4);
        a.x = fmaxf(a.x, 0.f); a.y = fmaxf(a.y, 0.f); a.z = fmaxf(a.z, 0.f); a.w = fmaxf(a.w, 0.f);
        aq[f4] = a;
        hq[f4] = *(const float4*)(h0 + (size_t)n * DD + f4 * 4);
    }
    agg[(size_t)n * DD + j] = 0.f;   // ready for next layer's atomics
    float h0j = h0[(size_t)n * DD + j];
    float gi0 = 0.f, gi1 = 0.f, gi2 = 0.f, gh0 = 0.f, gh1 = 0.f, gh2 = 0.f;
    #pragma unroll
    for (int f4 = 0; f4 < 8; ++f4) {
        #pragma unroll
        for (int dd = 0; dd < 4; ++dd) {
            int f = f4 * 4 + dd;
            float a = (&aq[f4].x)[dd], hh = (&hq[f4].x)[dd];
            gi0 = fmaf(a, sWT[0][0][f][j], gi0);
            gi1 = fmaf(a, sWT[0][1][f][j], gi1);
            gi2 = fmaf(a, sWT[0][2][f][j], gi2);
            gh0 = fmaf(hh, sWT[1][0][f][j], gh0);
            gh1 = fmaf(hh, sWT[1][1][f][j], gh1);
            gh2 = fmaf(hh, sWT[1][2][f][j], gh2);
        }
    }
    float r = sigmoidf_(gi0 + sbih[j] + gh0 + sbhh[j]);
    float z = sigmoidf_(gi1 + sbih[DD + j] + gh1 + sbhh[DD + j]);
    float nn = tanhf(gi2 + sbih[2 * DD + j] + r * (gh2 + sbhh[2 * DD + j]));
    float hnew = (1.f - z) * nn + z * h0j;
    float mu = hnew;
    #pragma unroll
    for (int o = 16; o; o >>= 1) mu += __shfl_xor(mu, o, 64);
    mu *= (1.f / DD);
    float d = hnew - mu;
    float var = d * d;
    #pragma unroll
    for (int o = 16; o; o >>= 1) var += __shfl_xor(var, o, 64);
    var *= (1.f / DD);
    float inv = rsqrtf(var + 1e-5f);
    h[(size_t)n * DD + j] = d * inv * sg[j] + sb[j];
}

// ---------------- fused Set2Set + prediction MLP: 256 threads per graph ----------------
__global__ __launch_bounds__(256) void k_s2s(const float* __restrict__ h,
                      const int* __restrict__ gstart,
                      const float* __restrict__ wih, const float* __restrict__ whh,
                      const float* __restrict__ bih, const float* __restrict__ bhh,
                      const float* __restrict__ Wp1, const float* __restrict__ bp1,
                      const float* __restrict__ Wp2, const float* __restrict__ bp2,
                      float* __restrict__ attbuf, float* __restrict__ out) {
    int g = blockIdx.x, tid = threadIdx.x;
    int s = gstart[g], e = gstart[g + 1], cnt = e - s;
    bool inlds = (cnt <= CAPN);
    __shared__ float sh[CAPN * 33];
    __shared__ float qs[64], shh[32], scc[32], gbuf[128];
    __shared__ float satt[256];
    __shared__ float red[4];
    __shared__ float rpart[8][32];
    if (inlds) {
        for (int idx = tid; idx < cnt * 32; idx += 256) {
            int v = idx >> 5, f = idx & 31;
            sh[v * 33 + f] = h[(size_t)(s + v) * 32 + f];
        }
    }
    if (tid < 64) qs[tid] = 0.f;
    if (tid < 32) { shh[tid] = 0.f; scc[tid] = 0.f; }
    __syncthreads();
    for (int it = 0; it < S2S; ++it) {
        if (tid < 128) {
            float gv = bih[tid] + bhh[tid];
            const float4* w4 = (const float4*)(wih + tid * 64);
            #pragma unroll
            for (int i = 0; i < 16; ++i) {
                float4 w = w4[i];
                gv += qs[4 * i] * w.x + qs[4 * i + 1] * w.y + qs[4 * i + 2] * w.z + qs[4 * i + 3] * w.w;
            }
            const float4* u4 = (const float4*)(whh + tid * 32);
            #pragma unroll
            for (int i = 0; i < 8; ++i) {
                float4 w = u4[i];
                gv += shh[4 * i] * w.x + shh[4 * i + 1] * w.y + shh[4 * i + 2] * w.z + shh[4 * i + 3] * w.w;
            }
            gbuf[tid] = gv;
        }
        __syncthreads();
        if (tid < 32) {
            float ii = gbuf[tid], ff = gbuf[32 + tid], gg = gbuf[64 + tid], oo = gbuf[96 + tid];
            float c = sigmoidf_(ff) * scc[tid] + sigmoidf_(ii) * tanhf(gg);
            scc[tid] = c;
            float hv = sigmoidf_(oo) * tanhf(c);
            shh[tid] = hv;
            qs[tid] = hv;
        }
        __syncthreads();
        float pmax = -1e30f;
        if (inlds) {
            float a = -1e30f;
            if (tid < cnt) {
                float acc = 0.f;
                #pragma unroll
                for (int f = 0; f < 32; ++f) acc += sh[tid * 33 + f] * shh[f];
                a = acc;
            }
            satt[tid] = a;
            pmax = a;
        } else {
            for (int v = tid; v < cnt; v += 256) {
                float acc = 0.f;
                const float* hp = h + (size_t)(s + v) * 32;
                #pragma unroll
                for (int f = 0; f < 32; ++f) acc += hp[f] * shh[f];
                attbuf[s + v] = acc;
                pmax = fmaxf(pmax, acc);
            }
        }
        #pragma unroll
        for (int o = 32; o; o >>= 1) pmax = fmaxf(pmax, __shfl_xor(pmax, o, 64));
        if ((tid & 63) == 0) red[tid >> 6] = pmax;
        __syncthreads();
        float m = fmaxf(fmaxf(red[0], red[1]), fmaxf(red[2], red[3]));
        float psum = 0.f;
        if (inlds) {
            if (tid < cnt) { float exv = __expf(satt[tid] - m); satt[tid] = exv; psum = exv; }
        } else {
            for (int v = tid; v < cnt; v += 256) {
                float exv = __expf(attbuf[s + v] - m); attbuf[s + v] = exv; psum += exv;
            }
        }
        #pragma unroll
        for (int o = 32; o; o >>= 1) psum += __shfl_xor(psum, o, 64);
        __syncthreads();
        if ((tid & 63) == 0) red[tid >> 6] = psum;
        __syncthreads();
        float denom = red[0] + red[1] + red[2] + red[3];
        int f = tid & 31, vc = tid >> 5;
        float racc = 0.f;
        if (inlds) {
            for (int v = vc; v < cnt; v += 8) racc += satt[v] * sh[v * 33 + f];
        } else {
            for (int v = vc; v < cnt; v += 8) racc += attbuf[s + v] * h[(size_t)(s + v) * 32 + f];
        }
        rpart[vc][f] = racc;
        __syncthreads();
        if (tid < 32) {
            float r = 0.f;
            #pragma unroll
            for (int c2 = 0; c2 < 8; ++c2) r += rpart[c2][tid];
            qs[32 + tid] = (cnt > 0) ? (r / denom) : 0.f;
        }
        __syncthreads();
    }
    if (tid < 32) {
        float u = bp1[tid];
        #pragma unroll
        for (int p = 0; p < 64; ++p) u += qs[p] * Wp1[p * 32 + tid];
        u = fmaxf(u, 0.f);
        float pr = u * Wp2[tid];
        #pragma unroll
        for (int o = 16; o; o >>= 1) pr += __shfl_xor(pr, o, 64);
        if (tid == 0) out[g] = pr + bp2[0];
    }
}

extern "C" void kernel_launch(void* const* d_in, const int* in_sizes, int n_in,
                              void* d_out, int out_size, void* d_ws, size_t ws_size,
                              hipStream_t stream) {
    const float* node = (const float*)d_in[0];
    const float* edge = (const float*)d_in[1];
    const int*   src  = (const int*)d_in[2];
    const int*   dst  = (const int*)d_in[3];
    const int*   n2g  = (const int*)d_in[4];
    const float* Wn   = (const float*)d_in[5];
    const float* bn   = (const float*)d_in[6];
    const float* We   = (const float*)d_in[7];
    const float* be   = (const float*)d_in[8];
    const float* eW1  = (const float*)d_in[9];
    const float* eb1  = (const float*)d_in[10];
    const float* eW2  = (const float*)d_in[11];
    const float* eb2  = (const float*)d_in[12];
    const float* gwih = (const float*)d_in[13];
    const float* gwhh = (const float*)d_in[14];
    const float* gbih = (const float*)d_in[15];
    const float* gbhh = (const float*)d_in[16];
    const float* lng  = (const float*)d_in[17];
    const float* lnb  = (const float*)d_in[18];
    const float* lwih = (const float*)d_in[19];
    const float* lwhh = (const float*)d_in[20];
    const float* lbih = (const float*)d_in[21];
    const float* lbhh = (const float*)d_in[22];
    const float* Wp1  = (const float*)d_in[23];
    const float* bp1  = (const float*)d_in[24];
    const float* Wp2  = (const float*)d_in[25];
    const float* bp2  = (const float*)d_in[26];

    float* ws = (float*)d_ws;
    float* h    = ws; ws += (size_t)NV * DD;
    float* h0   = ws; ws += (size_t)NV * DD;
    float* e_h  = ws; ws += (size_t)NE * DD;
    float* t3   = ws; ws += (size_t)NE * 64 * NDEPTH;
    float* agg  = ws; ws += (size_t)NV * DD;
    float* attbuf = ws; ws += NV;
    int* deg     = (int*)ws; ws += NV;
    int* cur     = (int*)ws; ws += NV;
    int* estart  = (int*)ws; ws += (NV + 1);
    int* esorted = (int*)ws; ws += NE;
    int* gstart  = (int*)ws; ws += (NG + 1);

    k_prolog<<<3755 + (NV + 255) / 256, 256, 0, stream>>>(node, Wn, bn, h, h0,
                                                          edge, We, be, e_h,
                                                          n2g, gstart, deg);
    k_hist<<<(NE + 255) / 256, 256, 0, stream>>>(src, deg);
    k_scan<<<1, SCAN_T, 0, stream>>>(deg, estart, cur);
    k_scatter<<<(NE + 255) / 256, 256, 0, stream>>>(src, cur, esorted);

    k_edge_t3<<<NDEPTH * (NE / EPB), 256, 0, stream>>>(e_h, eW1, eb1, t3, agg);

    for (int l = 0; l < NDEPTH; ++l) {
        k_fused<<<NV / NBK, 1024, 0, stream>>>(h, eW2 + (size_t)l * 64 * 1024, eb2 + l * 1024,
                                               t3 + (size_t)l * NE * 64, dst, estart, esorted, agg);
        k_gru_ln<<<NV / 8, 256, 0, stream>>>(agg, h0,
                                             gwih + (size_t)l * 96 * DD, gwhh + (size_t)l * 96 * DD,
                                             gbih + l * 96, gbhh + l * 96,
                                             lng + l * DD, lnb + l * DD, h);
    }

    k_s2s<<<NG, 256, 0, stream>>>(h, gstart, lwih, lwhh, lbih, lbhh, Wp1, bp1, Wp2, bp2,
                                  attbuf, (float*)d_out);
}

// Round 12
// 860.404 us; speedup vs baseline: 1.0393x; 1.0393x over previous
//
#include <hip/hip_runtime.h>
#include <math.h>

#define NV 20000
#define NE 100000
#define DD 32
#define NG 1000
#define NDEPTH 3
#define S2S 6
#define NBK 8    // src-nodes per block in k_fused
#define EPB 32   // edges per block in k_edge_t3
#define CAPN 128 // max nodes of one graph staged in LDS
#define SCAN_T 256
#define SCAN_C 80  // 256*80 = 20480 >= NV

__device__ __forceinline__ float sigmoidf_(float x) { return 1.0f / (1.0f + __expf(-x)); }

// ---------------- prolog: embed_node | embed_edge | graph bounds | deg zero ----------------
__global__ void k_prolog(const float* __restrict__ node, const float* __restrict__ Wn,
                         const float* __restrict__ bn, float* __restrict__ h,
                         float* __restrict__ h0,
                         const float* __restrict__ edge, const float* __restrict__ We,
                         const float* __restrict__ be, float* __restrict__ e_h,
                         const int* __restrict__ n2g, int* __restrict__ gstart,
                         int* __restrict__ deg) {
    __shared__ float sWn[36 * DD];
    __shared__ float sbn[DD];
    __shared__ float sxn[32][36];
    __shared__ float sWe[12 * DD];
    __shared__ float sbe[DD];
    __shared__ float sxe[32][12];
    int tid = threadIdx.x;
    int b = blockIdx.x;
    if (b < 625) {
        for (int i = tid; i < 36 * DD; i += 256) sWn[i] = Wn[i];
        if (tid < DD) sbn[tid] = bn[tid];
        int v0 = b * 32;
        for (int i = tid; i < 32 * 36; i += 256) sxn[i / 36][i % 36] = node[(size_t)v0 * 36 + i];
        __syncthreads();
        int f = tid & 31;
        int nb = tid >> 5;
        for (int g = 0; g < 4; ++g) {
            int n = nb + 8 * g;
            float acc = sbn[f];
            #pragma unroll
            for (int i = 0; i < 36; ++i) acc += sxn[n][i] * sWn[i * DD + f];
            float y = acc > 0.f ? acc : 0.01f * acc;
            h[(size_t)(v0 + n) * DD + f] = y;
            h0[(size_t)(v0 + n) * DD + f] = y;
        }
    } else if (b < 3750) {
        for (int i = tid; i < 12 * DD; i += 256) sWe[i] = We[i];
        if (tid < DD) sbe[tid] = be[tid];
        int e0 = (b - 625) * 32;
        for (int i = tid; i < 32 * 12; i += 256) sxe[i / 12][i % 12] = edge[(size_t)e0 * 12 + i];
        __syncthreads();
        int f = tid & 31;
        int nb = tid >> 5;
        for (int g = 0; g < 4; ++g) {
            int n = nb + 8 * g;
            float acc = sbe[f];
            #pragma unroll
            for (int i = 0; i < 12; ++i) acc += sxe[n][i] * sWe[i * DD + f];
            float y = acc > 0.f ? acc : 0.01f * acc;
            e_h[(size_t)(e0 + n) * DD + f] = y;
        }
    } else if (b < 3755) {
        int g = (b - 3750) * 256 + tid;
        if (g <= NG) {
            int lo = 0, hi = NV;
            while (lo < hi) {
                int mid = (lo + hi) >> 1;
                if (n2g[mid] < g) lo = mid + 1; else hi = mid;
            }
            gstart[g] = lo;
        }
    } else {
        int i = (b - 3755) * 256 + tid;
        if (i < NV) deg[i] = 0;
    }
}

// ---------------- CSR build ----------------
__global__ void k_hist(const int* __restrict__ src, int* __restrict__ deg) {
    int e = blockIdx.x * blockDim.x + threadIdx.x;
    if (e < NE) atomicAdd(&deg[src[e]], 1);
}

__global__ void k_scan(const int* __restrict__ deg, int* __restrict__ estart, int* __restrict__ cur) {
    __shared__ int sdeg[SCAN_T * SCAN_C];
    __shared__ int spart[SCAN_T];
    int tid = threadIdx.x;
    for (int i = tid; i < SCAN_T * SCAN_C; i += SCAN_T) sdeg[i] = (i < NV) ? deg[i] : 0;
    __syncthreads();
    int base = tid * SCAN_C;
    int sum = 0;
    for (int j = 0; j < SCAN_C; ++j) sum += sdeg[base + j];
    spart[tid] = sum;
    __syncthreads();
    for (int off = 1; off < SCAN_T; off <<= 1) {
        int v = (tid >= off) ? spart[tid - off] : 0;
        __syncthreads();
        spart[tid] += v;
        __syncthreads();
    }
    int run = spart[tid] - sum;
    for (int j = 0; j < SCAN_C; ++j) {
        int idx = base + j;
        if (idx < NV) { estart[idx] = run; cur[idx] = run; }
        run += sdeg[base + j];
    }
    if (tid == SCAN_T - 1) estart[NV] = run;
}

__global__ void k_scatter(const int* __restrict__ src, int* __restrict__ cur,
                          int* __restrict__ esorted) {
    int e = blockIdx.x * blockDim.x + threadIdx.x;
    if (e < NE) {
        int s = src[e];
        int pos = atomicAdd(&cur[s], 1);
        esorted[pos] = e;
    }
}

// ---------------- all-layer edge hidden: t[l] = relu(e_h @ eW1[l] + eb1[l]) ----------------
// 3*(NE/EPB) blocks. Also zeroes BOTH agg buffers (first 5000 blocks).
__global__ void k_edge_t3(const float* __restrict__ e_h, const float* __restrict__ eW1,
                          const float* __restrict__ eb1, float* __restrict__ t3,
                          float* __restrict__ aggAB) {
    __shared__ float sW[DD * 64];
    __shared__ float sb[64];
    int tid = threadIdx.x;
    int b = blockIdx.x;
    if (b < (2 * NV * DD) / 256) aggAB[(size_t)b * 256 + tid] = 0.f;
    int l = b / (NE / EPB), bb = b % (NE / EPB);
    const float* W = eW1 + (size_t)l * DD * 64;
    float* t = t3 + (size_t)l * NE * 64;
    for (int i = tid; i < DD * 64; i += 256) sW[i] = W[i];
    if (tid < 64) sb[tid] = eb1[l * 64 + tid];
    int e0 = bb * EPB;
    __syncthreads();
    int k = tid & 63;
    int nb = tid >> 6;
    float acc[8];
    #pragma unroll
    for (int g = 0; g < 8; ++g) acc[g] = sb[k];
    #pragma unroll
    for (int d4 = 0; d4 < 8; ++d4) {
        float4 ex[8];
        #pragma unroll
        for (int g = 0; g < 8; ++g)
            ex[g] = *(const float4*)(e_h + (size_t)(e0 + nb + 4 * g) * DD + d4 * 4);
        #pragma unroll
        for (int dd = 0; dd < 4; ++dd) {
            float w = sW[(d4 * 4 + dd) * 64 + k];
            #pragma unroll
            for (int g = 0; g < 8; ++g)
                acc[g] = fmaf((&ex[g].x)[dd], w, acc[g]);
        }
    }
    #pragma unroll
    for (int g = 0; g < 8; ++g)
        t[(size_t)(e0 + nb + 4 * g) * 64 + k] = fmaxf(acc[g], 0.f);
}

// ---------------- fused: [GRU+LN for own 8 nodes] + A in LDS + edge phase ----------------
// LAYER0=1: h from global. LAYER0=0: GRU(aggprev, h0) -> hbuf (LDS), zero aggprev slots.
// Phase-1/2 identical to the verified r9 kernel (readlane broadcasts, bpermute t).
template<int LAYER0>
__global__ __launch_bounds__(1024, 8) void k_fused_t(const float* __restrict__ hglob,
        const float* __restrict__ h0, float* __restrict__ aggprev,
        const float* __restrict__ wih, const float* __restrict__ whh,
        const float* __restrict__ bih, const float* __restrict__ bhh,
        const float* __restrict__ lng, const float* __restrict__ lnb,
        const float* __restrict__ eW2, const float* __restrict__ eb2,
        const float* __restrict__ t, const int* __restrict__ dst,
        const int* __restrict__ estart, const int* __restrict__ esorted,
        float* __restrict__ agg) {
    int v0 = blockIdx.x * NBK;
    __shared__ float sA[NBK][64][32];   // 64 KB, [n][k][f]
    __shared__ float sbb[NBK][32];
    __shared__ __align__(16) float hbuf[NBK][32];
    int tid = threadIdx.x;
    int lane = tid & 63;

    if constexpr (!LAYER0) {
        if (tid < 256) {
            int n = tid >> 5, j = tid & 31;
            int v = v0 + n;
            float gi0 = 0.f, gi1 = 0.f, gi2 = 0.f, gh0 = 0.f, gh1 = 0.f, gh2 = 0.f;
            #pragma unroll
            for (int f4 = 0; f4 < 8; ++f4) {
                float4 a4 = *(const float4*)(aggprev + (size_t)v * DD + f4 * 4);
                a4.x = fmaxf(a4.x, 0.f); a4.y = fmaxf(a4.y, 0.f);
                a4.z = fmaxf(a4.z, 0.f); a4.w = fmaxf(a4.w, 0.f);
                float4 h4 = *(const float4*)(h0 + (size_t)v * DD + f4 * 4);
                const float* wb = wih + j * 32 + f4 * 4;
                float4 wr = *(const float4*)(wb);
                float4 wz = *(const float4*)(wb + 1024);
                float4 wn = *(const float4*)(wb + 2048);
                const float* ub = whh + j * 32 + f4 * 4;
                float4 ur = *(const float4*)(ub);
                float4 uz = *(const float4*)(ub + 1024);
                float4 un = *(const float4*)(ub + 2048);
                gi0 += a4.x * wr.x + a4.y * wr.y + a4.z * wr.z + a4.w * wr.w;
                gi1 += a4.x * wz.x + a4.y * wz.y + a4.z * wz.z + a4.w * wz.w;
                gi2 += a4.x * wn.x + a4.y * wn.y + a4.z * wn.z + a4.w * wn.w;
                gh0 += h4.x * ur.x + h4.y * ur.y + h4.z * ur.z + h4.w * ur.w;
                gh1 += h4.x * uz.x + h4.y * uz.y + h4.z * uz.z + h4.w * uz.w;
                gh2 += h4.x * un.x + h4.y * un.y + h4.z * un.z + h4.w * un.w;
            }
            aggprev[(size_t)v * DD + j] = 0.f;   // ready for the layer after next
            float h0j = h0[(size_t)v * DD + j];
            float r = sigmoidf_(gi0 + bih[j] + gh0 + bhh[j]);
            float z = sigmoidf_(gi1 + bih[DD + j] + gh1 + bhh[DD + j]);
            float nn = tanhf(gi2 + bih[2 * DD + j] + r * (gh2 + bhh[2 * DD + j]));
            float hnew = (1.f - z) * nn + z * h0j;
            float mu = hnew;
            #pragma unroll
            for (int o = 16; o; o >>= 1) mu += __shfl_xor(mu, o, 64);
            mu *= (1.f / DD);
            float d = hnew - mu;
            float var = d * d;
            #pragma unroll
            for (int o = 16; o; o >>= 1) var += __shfl_xor(var, o, 64);
            var *= (1.f / DD);
            float inv = rsqrtf(var + 1e-5f);
            hbuf[n][j] = d * inv * lng[j] + lnb[j];
        }
        __syncthreads();
    }

    // wave-register h tile: lane l holds h[v0 + (l>>3)][4*(l&7) .. +3] (every wave)
    float4 hv4;
    if constexpr (LAYER0)
        hv4 = *(const float4*)(hglob + (size_t)(v0 + (lane >> 3)) * DD + 4 * (lane & 7));
    else
        hv4 = *(const float4*)(&hbuf[lane >> 3][4 * (lane & 7)]);
    float ha[4] = {hv4.x, hv4.y, hv4.z, hv4.w};

    int f = tid & 31;
    int kb = tid >> 5;                  // 0..31
    const float* wbase = eW2 + kb * 1024 + f;

    float acc[2][8];
    #pragma unroll
    for (int jj = 0; jj < 2; ++jj)
        #pragma unroll
        for (int n = 0; n < 8; ++n) acc[jj][n] = 0.f;

    #pragma unroll
    for (int d4 = 0; d4 < 8; ++d4) {
        float hs[8][4];
        #pragma unroll
        for (int n = 0; n < 8; ++n)
            #pragma unroll
            for (int dd = 0; dd < 4; ++dd)
                hs[n][dd] = __builtin_bit_cast(float,
                    __builtin_amdgcn_readlane(__builtin_bit_cast(int, ha[dd]), n * 8 + d4));
        #pragma unroll
        for (int jj = 0; jj < 2; ++jj) {
            const float* wp = wbase + jj * 32 * 1024 + d4 * 4 * 32;
            #pragma unroll
            for (int dd = 0; dd < 4; ++dd) {
                float w = wp[dd * 32];
                #pragma unroll
                for (int n = 0; n < 8; ++n) acc[jj][n] = fmaf(hs[n][dd], w, acc[jj][n]);
            }
        }
    }
    #pragma unroll
    for (int jj = 0; jj < 2; ++jj)
        #pragma unroll
        for (int n = 0; n < 8; ++n)
            sA[n][kb + 32 * jj][f] = acc[jj][n];

    if (tid < 256) {
        int n = tid >> 5;
        float bacc = 0.f;
        #pragma unroll
        for (int d = 0; d < DD; ++d) {
            float hvv = __shfl(ha[d & 3], n * 8 + (d >> 2), 64);
            bacc = fmaf(hvv, eb2[d * 32 + f], bacc);
        }
        sbb[n][f] = bacc;
    }
    __syncthreads();

    // edge phase: wave w -> node w>>1, edge parity w&1; A in registers; 2-stage pipeline.
    int w = tid >> 6;
    int n = w >> 1;
    int par = w & 1;
    int hf = lane >> 5;
    float Areg[32];
    #pragma unroll
    for (int q = 0; q < 32; ++q)
        Areg[q] = sA[n][2 * q + hf][f];
    float bbv = sbb[n][f];
    int i = estart[v0 + n] + par, e1 = estart[v0 + n + 1];
    if (i < e1) {
        int e = esorted[i];
        float tv = t[(size_t)e * 64 + lane];
        int dn = dst[e];
        while (i < e1) {
            i += 2;
            float tv2 = 0.f; int dn2 = 0;
            if (i < e1) {
                int e2 = esorted[i];
                tv2 = t[(size_t)e2 * 64 + lane];
                dn2 = dst[e2];
            }
            float m0 = 0.f, m1 = 0.f, m2 = 0.f, m3 = 0.f;
            #pragma unroll
            for (int q = 0; q < 32; q += 4) {
                m0 = fmaf(__shfl(tv, 2 * q + hf, 64),       Areg[q],     m0);
                m1 = fmaf(__shfl(tv, 2 * (q + 1) + hf, 64), Areg[q + 1], m1);
                m2 = fmaf(__shfl(tv, 2 * (q + 2) + hf, 64), Areg[q + 2], m2);
                m3 = fmaf(__shfl(tv, 2 * (q + 3) + hf, 64), Areg[q + 3], m3);
            }
            float m = (m0 + m1) + (m2 + m3);
            m += __shfl_xor(m, 32, 64);
            if (lane < 32) atomicAdd(&agg[(size_t)dn * DD + f], m + bbv);
            tv = tv2; dn = dn2;
        }
    }
}

// ---------------- final GRU + LayerNorm (8 nodes/block) ----------------
__global__ __launch_bounds__(256, 2) void k_gru_ln(float* __restrict__ agg,
                         const float* __restrict__ h0,
                         const float* __restrict__ wih, const float* __restrict__ whh,
                         const float* __restrict__ bih, const float* __restrict__ bhh,
                         const float* __restrict__ lng, const float* __restrict__ lnb,
                         float* __restrict__ h) {
    __shared__ float sWT[2][3][32][33];   // [ih/hh][gate][f][j], j-dim padded
    __shared__ float sbih[96], sbhh[96], sg[DD], sb[DD];
    int tid = threadIdx.x;
    for (int i = tid; i < 3072; i += 256) {
        int g = i >> 10, j = (i >> 5) & 31, f = i & 31;
        sWT[0][g][f][j] = wih[i];
        sWT[1][g][f][j] = whh[i];
    }
    if (tid < 96) { sbih[tid] = bih[tid]; sbhh[tid] = bhh[tid]; }
    if (tid < DD) { sg[tid] = lng[tid]; sb[tid] = lnb[tid]; }
    int v0 = blockIdx.x * 8;
    __syncthreads();
    int j = tid & 31;
    int n = v0 + (tid >> 5);
    float4 aq[8], hq[8];
    #pragma unroll
    for (int f4 = 0; f4 < 8; ++f4) {
        float4 a = *(const float4*)(agg + (size_t)n * DD + f4 * 4);
        a.x = fmaxf(a.x, 0.f); a.y = fmaxf(a.y, 0.f); a.z = fmaxf(a.z, 0.f); a.w = fmaxf(a.w, 0.f);
        aq[f4] = a;
        hq[f4] = *(const float4*)(h0 + (size_t)n * DD + f4 * 4);
    }
    float h0j = h0[(size_t)n * DD + j];
    float gi0 = 0.f, gi1 = 0.f, gi2 = 0.f, gh0 = 0.f, gh1 = 0.f, gh2 = 0.f;
    #pragma unroll
    for (int f4 = 0; f4 < 8; ++f4) {
        #pragma unroll
        for (int dd = 0; dd < 4; ++dd) {
            int f = f4 * 4 + dd;
            float a = (&aq[f4].x)[dd], hh = (&hq[f4].x)[dd];
            gi0 = fmaf(a, sWT[0][0][f][j], gi0);
            gi1 = fmaf(a, sWT[0][1][f][j], gi1);
            gi2 = fmaf(a, sWT[0][2][f][j], gi2);
            gh0 = fmaf(hh, sWT[1][0][f][j], gh0);
            gh1 = fmaf(hh, sWT[1][1][f][j], gh1);
            gh2 = fmaf(hh, sWT[1][2][f][j], gh2);
        }
    }
    float r = sigmoidf_(gi0 + sbih[j] + gh0 + sbhh[j]);
    float z = sigmoidf_(gi1 + sbih[DD + j] + gh1 + sbhh[DD + j]);
    float nn = tanhf(gi2 + sbih[2 * DD + j] + r * (gh2 + sbhh[2 * DD + j]));
    float hnew = (1.f - z) * nn + z * h0j;
    float mu = hnew;
    #pragma unroll
    for (int o = 16; o; o >>= 1) mu += __shfl_xor(mu, o, 64);
    mu *= (1.f / DD);
    float d = hnew - mu;
    float var = d * d;
    #pragma unroll
    for (int o = 16; o; o >>= 1) var += __shfl_xor(var, o, 64);
    var *= (1.f / DD);
    float inv = rsqrtf(var + 1e-5f);
    h[(size_t)n * DD + j] = d * inv * sg[j] + sb[j];
}

// ---------------- fused Set2Set + prediction MLP: 256 threads per graph ----------------
__global__ __launch_bounds__(256) void k_s2s(const float* __restrict__ h,
                      const int* __restrict__ gstart,
                      const float* __restrict__ wih, const float* __restrict__ whh,
                      const float* __restrict__ bih, const float* __restrict__ bhh,
                      const float* __restrict__ Wp1, const float* __restrict__ bp1,
                      const float* __restrict__ Wp2, const float* __restrict__ bp2,
                      float* __restrict__ attbuf, float* __restrict__ out) {
    int g = blockIdx.x, tid = threadIdx.x;
    int s = gstart[g], e = gstart[g + 1], cnt = e - s;
    bool inlds = (cnt <= CAPN);
    __shared__ float sh[CAPN * 33];
    __shared__ float qs[64], shh[32], scc[32], gbuf[128];
    __shared__ float satt[256];
    __shared__ float red[4];
    __shared__ float rpart[8][32];
    if (inlds) {
        for (int idx = tid; idx < cnt * 32; idx += 256) {
            int v = idx >> 5, f = idx & 31;
            sh[v * 33 + f] = h[(size_t)(s + v) * 32 + f];
        }
    }
    if (tid < 64) qs[tid] = 0.f;
    if (tid < 32) { shh[tid] = 0.f; scc[tid] = 0.f; }
    __syncthreads();
    for (int it = 0; it < S2S; ++it) {
        if (tid < 128) {
            float gv = bih[tid] + bhh[tid];
            const float4* w4 = (const float4*)(wih + tid * 64);
            #pragma unroll
            for (int i = 0; i < 16; ++i) {
                float4 w = w4[i];
                gv += qs[4 * i] * w.x + qs[4 * i + 1] * w.y + qs[4 * i + 2] * w.z + qs[4 * i + 3] * w.w;
            }
            const float4* u4 = (const float4*)(whh + tid * 32);
            #pragma unroll
            for (int i = 0; i < 8; ++i) {
                float4 w = u4[i];
                gv += shh[4 * i] * w.x + shh[4 * i + 1] * w.y + shh[4 * i + 2] * w.z + shh[4 * i + 3] * w.w;
            }
            gbuf[tid] = gv;
        }
        __syncthreads();
        if (tid < 32) {
            float ii = gbuf[tid], ff = gbuf[32 + tid], gg = gbuf[64 + tid], oo = gbuf[96 + tid];
            float c = sigmoidf_(ff) * scc[tid] + sigmoidf_(ii) * tanhf(gg);
            scc[tid] = c;
            float hv = sigmoidf_(oo) * tanhf(c);
            shh[tid] = hv;
            qs[tid] = hv;
        }
        __syncthreads();
        float pmax = -1e30f;
        if (inlds) {
            float a = -1e30f;
            if (tid < cnt) {
                float acc = 0.f;
                #pragma unroll
                for (int f = 0; f < 32; ++f) acc += sh[tid * 33 + f] * shh[f];
                a = acc;
            }
            satt[tid] = a;
            pmax = a;
        } else {
            for (int v = tid; v < cnt; v += 256) {
                float acc = 0.f;
                const float* hp = h + (size_t)(s + v) * 32;
                #pragma unroll
                for (int f = 0; f < 32; ++f) acc += hp[f] * shh[f];
                attbuf[s + v] = acc;
                pmax = fmaxf(pmax, acc);
            }
        }
        #pragma unroll
        for (int o = 32; o; o >>= 1) pmax = fmaxf(pmax, __shfl_xor(pmax, o, 64));
        if ((tid & 63) == 0) red[tid >> 6] = pmax;
        __syncthreads();
        float m = fmaxf(fmaxf(red[0], red[1]), fmaxf(red[2], red[3]));
        float psum = 0.f;
        if (inlds) {
            if (tid < cnt) { float exv = __expf(satt[tid] - m); satt[tid] = exv; psum = exv; }
        } else {
            for (int v = tid; v < cnt; v += 256) {
                float exv = __expf(attbuf[s + v] - m); attbuf[s + v] = exv; psum += exv;
            }
        }
        #pragma unroll
        for (int o = 32; o; o >>= 1) psum += __shfl_xor(psum, o, 64);
        __syncthreads();
        if ((tid & 63) == 0) red[tid >> 6] = psum;
        __syncthreads();
        float denom = red[0] + red[1] + red[2] + red[3];
        int f = tid & 31, vc = tid >> 5;
        float racc = 0.f;
        if (inlds) {
            for (int v = vc; v < cnt; v += 8) racc += satt[v] * sh[v * 33 + f];
        } else {
            for (int v = vc; v < cnt; v += 8) racc += attbuf[s + v] * h[(size_t)(s + v) * 32 + f];
        }
        rpart[vc][f] = racc;
        __syncthreads();
        if (tid < 32) {
            float r = 0.f;
            #pragma unroll
            for (int c2 = 0; c2 < 8; ++c2) r += rpart[c2][tid];
            qs[32 + tid] = (cnt > 0) ? (r / denom) : 0.f;
        }
        __syncthreads();
    }
    if (tid < 32) {
        float u = bp1[tid];
        #pragma unroll
        for (int p = 0; p < 64; ++p) u += qs[p] * Wp1[p * 32 + tid];
        u = fmaxf(u, 0.f);
        float pr = u * Wp2[tid];
        #pragma unroll
        for (int o = 16; o; o >>= 1) pr += __shfl_xor(pr, o, 64);
        if (tid == 0) out[g] = pr + bp2[0];
    }
}

extern "C" void kernel_launch(void* const* d_in, const int* in_sizes, int n_in,
                              void* d_out, int out_size, void* d_ws, size_t ws_size,
                              hipStream_t stream) {
    const float* node = (const float*)d_in[0];
    const float* edge = (const float*)d_in[1];
    const int*   src  = (const int*)d_in[2];
    const int*   dst  = (const int*)d_in[3];
    const int*   n2g  = (const int*)d_in[4];
    const float* Wn   = (const float*)d_in[5];
    const float* bn   = (const float*)d_in[6];
    const float* We   = (const float*)d_in[7];
    const float* be   = (const float*)d_in[8];
    const float* eW1  = (const float*)d_in[9];
    const float* eb1  = (const float*)d_in[10];
    const float* eW2  = (const float*)d_in[11];
    const float* eb2  = (const float*)d_in[12];
    const float* gwih = (const float*)d_in[13];
    const float* gwhh = (const float*)d_in[14];
    const float* gbih = (const float*)d_in[15];
    const float* gbhh = (const float*)d_in[16];
    const float* lng  = (const float*)d_in[17];
    const float* lnb  = (const float*)d_in[18];
    const float* lwih = (const float*)d_in[19];
    const float* lwhh = (const float*)d_in[20];
    const float* lbih = (const float*)d_in[21];
    const float* lbhh = (const float*)d_in[22];
    const float* Wp1  = (const float*)d_in[23];
    const float* bp1  = (const float*)d_in[24];
    const float* Wp2  = (const float*)d_in[25];
    const float* bp2  = (const float*)d_in[26];

    float* ws = (float*)d_ws;
    float* h    = ws; ws += (size_t)NV * DD;
    float* h0   = ws; ws += (size_t)NV * DD;
    float* e_h  = ws; ws += (size_t)NE * DD;
    float* t3   = ws; ws += (size_t)NE * 64 * NDEPTH;
    float* aggA = ws; ws += (size_t)NV * DD;
    float* aggB = ws; ws += (size_t)NV * DD;
    float* attbuf = ws; ws += NV;
    int* deg     = (int*)ws; ws += NV;
    int* cur     = (int*)ws; ws += NV;
    int* estart  = (int*)ws; ws += (NV + 1);
    int* esorted = (int*)ws; ws += NE;
    int* gstart  = (int*)ws; ws += (NG + 1);

    k_prolog<<<3755 + (NV + 255) / 256, 256, 0, stream>>>(node, Wn, bn, h, h0,
                                                          edge, We, be, e_h,
                                                          n2g, gstart, deg);
    k_hist<<<(NE + 255) / 256, 256, 0, stream>>>(src, deg);
    k_scan<<<1, SCAN_T, 0, stream>>>(deg, estart, cur);
    k_scatter<<<(NE + 255) / 256, 256, 0, stream>>>(src, cur, esorted);

    // all three layers' t in one launch (+ zero of both agg buffers; aggA,aggB contiguous)
    k_edge_t3<<<NDEPTH * (NE / EPB), 256, 0, stream>>>(e_h, eW1, eb1, t3, aggA);

    // layer 0: h = embedding, atomics -> aggA
    k_fused_t<1><<<NV / NBK, 1024, 0, stream>>>(h, h0, nullptr,
                                                nullptr, nullptr, nullptr, nullptr, nullptr, nullptr,
                                                eW2, eb2, t3, dst, estart, esorted, aggA);
    // layer 1: GRU(aggA, h0) with layer-0 params -> local h; zero aggA; atomics -> aggB
    k_fused_t<0><<<NV / NBK, 1024, 0, stream>>>(nullptr, h0, aggA,
                                                gwih, gwhh, gbih, gbhh, lng, lnb,
                                                eW2 + 65536, eb2 + 1024,
                                                t3 + (size_t)NE * 64, dst, estart, esorted, aggB);
    // layer 2: GRU(aggB, h0) with layer-1 params -> local h; zero aggB; atomics -> aggA
    k_fused_t<0><<<NV / NBK, 1024, 0, stream>>>(nullptr, h0, aggB,
                                                gwih + 3072, gwhh + 3072, gbih + 96, gbhh + 96,
                                                lng + DD, lnb + DD,
                                                eW2 + 131072, eb2 + 2048,
                                                t3 + (size_t)2 * NE * 64, dst, estart, esorted, aggA);
    // final GRU+LN with layer-2 params -> global h for Set2Set
    k_gru_ln<<<NV / 8, 256, 0, stream>>>(aggA, h0,
                                         gwih + 6144, gwhh + 6144, gbih + 192, gbhh + 192,
                                         lng + 2 * DD, lnb + 2 * DD, h);

    k_s2s<<<NG, 256, 0, stream>>>(h, gstart, lwih, lwhh, lbih, lbhh, Wp1, bp1, Wp2, bp2,
                                  attbuf, (float*)d_out);
}

// Round 13
// 567.805 us; speedup vs baseline: 1.5749x; 1.5153x over previous
//
#include <hip/hip_runtime.h>
#include <math.h>

#define NV 20000
#define NE 100000
#define DD 32
#define NG 1000
#define NDEPTH 3
#define S2S 6
#define NBK 8    // src-nodes per block in k_fused
#define EPB 16   // edges per block in k_edge_t3
#define CAPN 128 // max nodes of one graph staged in LDS
#define SCAN_T 256
#define SCAN_C 80  // 256*80 = 20480 >= NV

__device__ __forceinline__ float sigmoidf_(float x) { return 1.0f / (1.0f + __expf(-x)); }

// ---------------- prolog: embed_node | embed_edge | graph bounds | deg zero ----------------
__global__ void k_prolog(const float* __restrict__ node, const float* __restrict__ Wn,
                         const float* __restrict__ bn, float* __restrict__ h,
                         float* __restrict__ h0,
                         const float* __restrict__ edge, const float* __restrict__ We,
                         const float* __restrict__ be, float* __restrict__ e_h,
                         const int* __restrict__ n2g, int* __restrict__ gstart,
                         int* __restrict__ deg) {
    __shared__ float sWn[36 * DD];
    __shared__ float sbn[DD];
    __shared__ float sxn[32][36];
    __shared__ float sWe[12 * DD];
    __shared__ float sbe[DD];
    __shared__ float sxe[32][12];
    int tid = threadIdx.x;
    int b = blockIdx.x;
    if (b < 625) {
        for (int i = tid; i < 36 * DD; i += 256) sWn[i] = Wn[i];
        if (tid < DD) sbn[tid] = bn[tid];
        int v0 = b * 32;
        for (int i = tid; i < 32 * 36; i += 256) sxn[i / 36][i % 36] = node[(size_t)v0 * 36 + i];
        __syncthreads();
        int f = tid & 31;
        int nb = tid >> 5;
        for (int g = 0; g < 4; ++g) {
            int n = nb + 8 * g;
            float acc = sbn[f];
            #pragma unroll
            for (int i = 0; i < 36; ++i) acc += sxn[n][i] * sWn[i * DD + f];
            float y = acc > 0.f ? acc : 0.01f * acc;
            h[(size_t)(v0 + n) * DD + f] = y;
            h0[(size_t)(v0 + n) * DD + f] = y;
        }
    } else if (b < 3750) {
        for (int i = tid; i < 12 * DD; i += 256) sWe[i] = We[i];
        if (tid < DD) sbe[tid] = be[tid];
        int e0 = (b - 625) * 32;
        for (int i = tid; i < 32 * 12; i += 256) sxe[i / 12][i % 12] = edge[(size_t)e0 * 12 + i];
        __syncthreads();
        int f = tid & 31;
        int nb = tid >> 5;
        for (int g = 0; g < 4; ++g) {
            int n = nb + 8 * g;
            float acc = sbe[f];
            #pragma unroll
            for (int i = 0; i < 12; ++i) acc += sxe[n][i] * sWe[i * DD + f];
            float y = acc > 0.f ? acc : 0.01f * acc;
            e_h[(size_t)(e0 + n) * DD + f] = y;
        }
    } else if (b < 3755) {
        int g = (b - 3750) * 256 + tid;
        if (g <= NG) {
            int lo = 0, hi = NV;
            while (lo < hi) {
                int mid = (lo + hi) >> 1;
                if (n2g[mid] < g) lo = mid + 1; else hi = mid;
            }
            gstart[g] = lo;
        }
    } else {
        int i = (b - 3755) * 256 + tid;
        if (i < NV) deg[i] = 0;
    }
}

// ---------------- CSR build ----------------
__global__ void k_scan(const int* __restrict__ deg, int* __restrict__ estart, int* __restrict__ cur) {
    __shared__ int sdeg[SCAN_T * SCAN_C];
    __shared__ int spart[SCAN_T];
    int tid = threadIdx.x;
    for (int i = tid; i < SCAN_T * SCAN_C; i += SCAN_T) sdeg[i] = (i < NV) ? deg[i] : 0;
    __syncthreads();
    int base = tid * SCAN_C;
    int sum = 0;
    for (int j = 0; j < SCAN_C; ++j) sum += sdeg[base + j];
    spart[tid] = sum;
    __syncthreads();
    for (int off = 1; off < SCAN_T; off <<= 1) {
        int v = (tid >= off) ? spart[tid - off] : 0;
        __syncthreads();
        spart[tid] += v;
        __syncthreads();
    }
    int run = spart[tid] - sum;
    for (int j = 0; j < SCAN_C; ++j) {
        int idx = base + j;
        if (idx < NV) { estart[idx] = run; cur[idx] = run; }
        run += sdeg[base + j];
    }
    if (tid == SCAN_T - 1) estart[NV] = run;
}

__global__ void k_scatter(const int* __restrict__ src, int* __restrict__ cur,
                          int* __restrict__ esorted) {
    int e = blockIdx.x * blockDim.x + threadIdx.x;
    if (e < NE) {
        int s = src[e];
        int pos = atomicAdd(&cur[s], 1);
        esorted[pos] = e;
    }
}

// ---------------- all-layer edge hidden + src histogram ----------------
// blocks [0, 3*(NE/EPB)): t[l] = relu(e_h @ eW1[l] + eb1[l]); first 2500 also zero agg.
// blocks [3*(NE/EPB), +391): histogram of src into deg.
__global__ void k_edge_t3(const float* __restrict__ e_h, const float* __restrict__ eW1,
                          const float* __restrict__ eb1, float* __restrict__ t3,
                          float* __restrict__ agg,
                          const int* __restrict__ src, int* __restrict__ deg) {
    __shared__ float sW[DD * 64];
    __shared__ float sb[64];
    int tid = threadIdx.x;
    int b = blockIdx.x;
    if (b >= NDEPTH * (NE / EPB)) {
        int e = (b - NDEPTH * (NE / EPB)) * 256 + tid;
        if (e < NE) atomicAdd(&deg[src[e]], 1);
        return;
    }
    if (b < (NV * DD) / 256) agg[(size_t)b * 256 + tid] = 0.f;
    int l = b / (NE / EPB), bb = b % (NE / EPB);
    const float* W = eW1 + (size_t)l * DD * 64;
    float* t = t3 + (size_t)l * NE * 64;
    for (int i = tid; i < DD * 64; i += 256) sW[i] = W[i];
    if (tid < 64) sb[tid] = eb1[l * 64 + tid];
    int e0 = bb * EPB;
    __syncthreads();
    int k = tid & 63;
    int nb = tid >> 6;
    float acc[4];
    #pragma unroll
    for (int g = 0; g < 4; ++g) acc[g] = sb[k];
    #pragma unroll
    for (int d4 = 0; d4 < 8; ++d4) {
        float4 ex[4];
        #pragma unroll
        for (int g = 0; g < 4; ++g)
            ex[g] = *(const float4*)(e_h + (size_t)(e0 + nb + 4 * g) * DD + d4 * 4);
        #pragma unroll
        for (int dd = 0; dd < 4; ++dd) {
            float w = sW[(d4 * 4 + dd) * 64 + k];
            #pragma unroll
            for (int g = 0; g < 4; ++g)
                acc[g] = fmaf((&ex[g].x)[dd], w, acc[g]);
        }
    }
    #pragma unroll
    for (int g = 0; g < 4; ++g)
        t[(size_t)(e0 + nb + 4 * g) * 64 + k] = fmaxf(acc[g], 0.f);
}

// ---------------- fused: per-tile A in LDS + per-node A-in-registers edge phase ----------------
// 1024 threads: phase-1 (kb 0..31, f 0..31), k = kb + 32*jj; phase-2: 2 waves/node.
__global__ __launch_bounds__(1024, 8) void k_fused(const float* __restrict__ h,
        const float* __restrict__ eW2, const float* __restrict__ eb2,
        const float* __restrict__ t, const int* __restrict__ dst,
        const int* __restrict__ estart, const int* __restrict__ esorted,
        float* __restrict__ agg) {
    int v0 = blockIdx.x * NBK;
    __shared__ float sA[NBK][64][32];   // 64 KB, [n][k][f]
    __shared__ float sbb[NBK][32];
    int tid = threadIdx.x;
    int lane = tid & 63;

    // wave-register h tile: lane l holds h[v0 + (l>>3)][4*(l&7) .. +3] (every wave)
    float4 hv4 = *(const float4*)(h + (size_t)(v0 + (lane >> 3)) * DD + 4 * (lane & 7));
    float ha[4] = {hv4.x, hv4.y, hv4.z, hv4.w};

    int f = tid & 31;
    int kb = tid >> 5;                  // 0..31
    const float* wbase = eW2 + kb * 1024 + f;

    float acc[2][8];
    #pragma unroll
    for (int jj = 0; jj < 2; ++jj)
        #pragma unroll
        for (int n = 0; n < 8; ++n) acc[jj][n] = 0.f;

    #pragma unroll
    for (int d4 = 0; d4 < 8; ++d4) {
        float hs[8][4];
        #pragma unroll
        for (int n = 0; n < 8; ++n)
            #pragma unroll
            for (int dd = 0; dd < 4; ++dd)
                hs[n][dd] = __builtin_bit_cast(float,
                    __builtin_amdgcn_readlane(__builtin_bit_cast(int, ha[dd]), n * 8 + d4));
        #pragma unroll
        for (int jj = 0; jj < 2; ++jj) {
            const float* wp = wbase + jj * 32 * 1024 + d4 * 4 * 32;
            #pragma unroll
            for (int dd = 0; dd < 4; ++dd) {
                float w = wp[dd * 32];
                #pragma unroll
                for (int n = 0; n < 8; ++n) acc[jj][n] = fmaf(hs[n][dd], w, acc[jj][n]);
            }
        }
    }
    #pragma unroll
    for (int jj = 0; jj < 2; ++jj)
        #pragma unroll
        for (int n = 0; n < 8; ++n)
            sA[n][kb + 32 * jj][f] = acc[jj][n];

    if (tid < 256) {
        int n = tid >> 5;
        float bacc = 0.f;
        #pragma unroll
        for (int d = 0; d < DD; ++d) {
            float hvv = __shfl(ha[d & 3], n * 8 + (d >> 2), 64);
            bacc = fmaf(hvv, eb2[d * 32 + f], bacc);
        }
        sbb[n][f] = bacc;
    }
    __syncthreads();

    // edge phase: wave w -> node w>>1, edge parity w&1; A in registers; 2-stage pipeline.
    int w = tid >> 6;
    int n = w >> 1;
    int par = w & 1;
    int hf = lane >> 5;
    float Areg[32];
    #pragma unroll
    for (int q = 0; q < 32; ++q)
        Areg[q] = sA[n][2 * q + hf][f];
    float bbv = sbb[n][f];
    int i = estart[v0 + n] + par, e1 = estart[v0 + n + 1];
    if (i < e1) {
        int e = esorted[i];
        float tv = t[(size_t)e * 64 + lane];
        int dn = dst[e];
        while (i < e1) {
            i += 2;
            float tv2 = 0.f; int dn2 = 0;
            if (i < e1) {
                int e2 = esorted[i];
                tv2 = t[(size_t)e2 * 64 + lane];
                dn2 = dst[e2];
            }
            float m0 = 0.f, m1 = 0.f, m2 = 0.f, m3 = 0.f;
            #pragma unroll
            for (int q = 0; q < 32; q += 4) {
                m0 = fmaf(__shfl(tv, 2 * q + hf, 64),       Areg[q],     m0);
                m1 = fmaf(__shfl(tv, 2 * (q + 1) + hf, 64), Areg[q + 1], m1);
                m2 = fmaf(__shfl(tv, 2 * (q + 2) + hf, 64), Areg[q + 2], m2);
                m3 = fmaf(__shfl(tv, 2 * (q + 3) + hf, 64), Areg[q + 3], m3);
            }
            float m = (m0 + m1) + (m2 + m3);
            m += __shfl_xor(m, 32, 64);
            if (lane < 32) atomicAdd(&agg[(size_t)dn * DD + f], m + bbv);
            tv = tv2; dn = dn2;
        }
    }
}

// ---------------- GRU + LayerNorm (8 nodes/block); re-zeroes agg for next layer ----------------
__global__ __launch_bounds__(256, 2) void k_gru_ln(float* __restrict__ agg,
                         const float* __restrict__ h0,
                         const float* __restrict__ wih, const float* __restrict__ whh,
                         const float* __restrict__ bih, const float* __restrict__ bhh,
                         const float* __restrict__ lng, const float* __restrict__ lnb,
                         float* __restrict__ h) {
    __shared__ float sWT[2][3][32][33];   // [ih/hh][gate][f][j], j-dim padded
    __shared__ float sbih[96], sbhh[96], sg[DD], sb[DD];
    int tid = threadIdx.x;
    for (int i = tid; i < 3072; i += 256) {
        int g = i >> 10, j = (i >> 5) & 31, f = i & 31;
        sWT[0][g][f][j] = wih[i];
        sWT[1][g][f][j] = whh[i];
    }
    if (tid < 96) { sbih[tid] = bih[tid]; sbhh[tid] = bhh[tid]; }
    if (tid < DD) { sg[tid] = lng[tid]; sb[tid] = lnb[tid]; }
    int v0 = blockIdx.x * 8;
    __syncthreads();
    int j = tid & 31;
    int n = v0 + (tid >> 5);
    float4 aq[8], hq[8];
    #pragma unroll
    for (int f4 = 0; f4 < 8; ++f4) {
        float4 a = *(const float4*)(agg + (size_t)n * DD + f4 * 4);
        a.x = fmaxf(a.x, 0.f); a.y = fmaxf(a.y, 0.f); a.z = fmaxf(a.z, 0.f); a.w = fmaxf(a.w, 0.f);
        aq[f4] = a;
        hq[f4] = *(const float4*)(h0 + (size_t)n * DD + f4 * 4);
    }
    agg[(size_t)n * DD + j] = 0.f;   // ready for next layer's atomics
    float h0j = h0[(size_t)n * DD + j];
    float gi0 = 0.f, gi1 = 0.f, gi2 = 0.f, gh0 = 0.f, gh1 = 0.f, gh2 = 0.f;
    #pragma unroll
    for (int f4 = 0; f4 < 8; ++f4) {
        #pragma unroll
        for (int dd = 0; dd < 4; ++dd) {
            int f = f4 * 4 + dd;
            float a = (&aq[f4].x)[dd], hh = (&hq[f4].x)[dd];
            gi0 = fmaf(a, sWT[0][0][f][j], gi0);
            gi1 = fmaf(a, sWT[0][1][f][j], gi1);
            gi2 = fmaf(a, sWT[0][2][f][j], gi2);
            gh0 = fmaf(hh, sWT[1][0][f][j], gh0);
            gh1 = fmaf(hh, sWT[1][1][f][j], gh1);
            gh2 = fmaf(hh, sWT[1][2][f][j], gh2);
        }
    }
    float r = sigmoidf_(gi0 + sbih[j] + gh0 + sbhh[j]);
    float z = sigmoidf_(gi1 + sbih[DD + j] + gh1 + sbhh[DD + j]);
    float nn = tanhf(gi2 + sbih[2 * DD + j] + r * (gh2 + sbhh[2 * DD + j]));
    float hnew = (1.f - z) * nn + z * h0j;
    float mu = hnew;
    #pragma unroll
    for (int o = 16; o; o >>= 1) mu += __shfl_xor(mu, o, 64);
    mu *= (1.f / DD);
    float d = hnew - mu;
    float var = d * d;
    #pragma unroll
    for (int o = 16; o; o >>= 1) var += __shfl_xor(var, o, 64);
    var *= (1.f / DD);
    float inv = rsqrtf(var + 1e-5f);
    h[(size_t)n * DD + j] = d * inv * sg[j] + sb[j];
}

// ---------------- fused Set2Set + prediction MLP: 256 threads per graph ----------------
__global__ __launch_bounds__(256) void k_s2s(const float* __restrict__ h,
                      const int* __restrict__ gstart,
                      const float* __restrict__ wih, const float* __restrict__ whh,
                      const float* __restrict__ bih, const float* __restrict__ bhh,
                      const float* __restrict__ Wp1, const float* __restrict__ bp1,
                      const float* __restrict__ Wp2, const float* __restrict__ bp2,
                      float* __restrict__ attbuf, float* __restrict__ out) {
    int g = blockIdx.x, tid = threadIdx.x;
    int s = gstart[g], e = gstart[g + 1], cnt = e - s;
    bool inlds = (cnt <= CAPN);
    __shared__ float sh[CAPN * 33];
    __shared__ float qs[64], shh[32], scc[32], gbuf[128];
    __shared__ float satt[256];
    __shared__ float red[4];
    __shared__ float rpart[8][32];
    if (inlds) {
        for (int idx = tid; idx < cnt * 32; idx += 256) {
            int v = idx >> 5, f = idx & 31;
            sh[v * 33 + f] = h[(size_t)(s + v) * 32 + f];
        }
    }
    if (tid < 64) qs[tid] = 0.f;
    if (tid < 32) { shh[tid] = 0.f; scc[tid] = 0.f; }
    __syncthreads();
    for (int it = 0; it < S2S; ++it) {
        if (tid < 128) {
            float gv = bih[tid] + bhh[tid];
            const float4* w4 = (const float4*)(wih + tid * 64);
            #pragma unroll
            for (int i = 0; i < 16; ++i) {
                float4 w = w4[i];
                gv += qs[4 * i] * w.x + qs[4 * i + 1] * w.y + qs[4 * i + 2] * w.z + qs[4 * i + 3] * w.w;
            }
            const float4* u4 = (const float4*)(whh + tid * 32);
            #pragma unroll
            for (int i = 0; i < 8; ++i) {
                float4 w = u4[i];
                gv += shh[4 * i] * w.x + shh[4 * i + 1] * w.y + shh[4 * i + 2] * w.z + shh[4 * i + 3] * w.w;
            }
            gbuf[tid] = gv;
        }
        __syncthreads();
        if (tid < 32) {
            float ii = gbuf[tid], ff = gbuf[32 + tid], gg = gbuf[64 + tid], oo = gbuf[96 + tid];
            float c = sigmoidf_(ff) * scc[tid] + sigmoidf_(ii) * tanhf(gg);
            scc[tid] = c;
            float hv = sigmoidf_(oo) * tanhf(c);
            shh[tid] = hv;
            qs[tid] = hv;
        }
        __syncthreads();
        float pmax = -1e30f;
        if (inlds) {
            float a = -1e30f;
            if (tid < cnt) {
                float acc = 0.f;
                #pragma unroll
                for (int f = 0; f < 32; ++f) acc += sh[tid * 33 + f] * shh[f];
                a = acc;
            }
            satt[tid] = a;
            pmax = a;
        } else {
            for (int v = tid; v < cnt; v += 256) {
                float acc = 0.f;
                const float* hp = h + (size_t)(s + v) * 32;
                #pragma unroll
                for (int f = 0; f < 32; ++f) acc += hp[f] * shh[f];
                attbuf[s + v] = acc;
                pmax = fmaxf(pmax, acc);
            }
        }
        #pragma unroll
        for (int o = 32; o; o >>= 1) pmax = fmaxf(pmax, __shfl_xor(pmax, o, 64));
        if ((tid & 63) == 0) red[tid >> 6] = pmax;
        __syncthreads();
        float m = fmaxf(fmaxf(red[0], red[1]), fmaxf(red[2], red[3]));
        float psum = 0.f;
        if (inlds) {
            if (tid < cnt) { float exv = __expf(satt[tid] - m); satt[tid] = exv; psum = exv; }
        } else {
            for (int v = tid; v < cnt; v += 256) {
                float exv = __expf(attbuf[s + v] - m); attbuf[s + v] = exv; psum += exv;
            }
        }
        #pragma unroll
        for (int o = 32; o; o >>= 1) psum += __shfl_xor(psum, o, 64);
        __syncthreads();
        if ((tid & 63) == 0) red[tid >> 6] = psum;
        __syncthreads();
        float denom = red[0] + red[1] + red[2] + red[3];
        int f = tid & 31, vc = tid >> 5;
        float racc = 0.f;
        if (inlds) {
            for (int v = vc; v < cnt; v += 8) racc += satt[v] * sh[v * 33 + f];
        } else {
            for (int v = vc; v < cnt; v += 8) racc += attbuf[s + v] * h[(size_t)(s + v) * 32 + f];
        }
        rpart[vc][f] = racc;
        __syncthreads();
        if (tid < 32) {
            float r = 0.f;
            #pragma unroll
            for (int c2 = 0; c2 < 8; ++c2) r += rpart[c2][tid];
            qs[32 + tid] = (cnt > 0) ? (r / denom) : 0.f;
        }
        __syncthreads();
    }
    if (tid < 32) {
        float u = bp1[tid];
        #pragma unroll
        for (int p = 0; p < 64; ++p) u += qs[p] * Wp1[p * 32 + tid];
        u = fmaxf(u, 0.f);
        float pr = u * Wp2[tid];
        #pragma unroll
        for (int o = 16; o; o >>= 1) pr += __shfl_xor(pr, o, 64);
        if (tid == 0) out[g] = pr + bp2[0];
    }
}

extern "C" void kernel_launch(void* const* d_in, const int* in_sizes, int n_in,
                              void* d_out, int out_size, void* d_ws, size_t ws_size,
                              hipStream_t stream) {
    const float* node = (const float*)d_in[0];
    const float* edge = (const float*)d_in[1];
    const int*   src  = (const int*)d_in[2];
    const int*   dst  = (const int*)d_in[3];
    const int*   n2g  = (const int*)d_in[4];
    const float* Wn   = (const float*)d_in[5];
    const float* bn   = (const float*)d_in[6];
    const float* We   = (const float*)d_in[7];
    const float* be   = (const float*)d_in[8];
    const float* eW1  = (const float*)d_in[9];
    const float* eb1  = (const float*)d_in[10];
    const float* eW2  = (const float*)d_in[11];
    const float* eb2  = (const float*)d_in[12];
    const float* gwih = (const float*)d_in[13];
    const float* gwhh = (const float*)d_in[14];
    const float* gbih = (const float*)d_in[15];
    const float* gbhh = (const float*)d_in[16];
    const float* lng  = (const float*)d_in[17];
    const float* lnb  = (const float*)d_in[18];
    const float* lwih = (const float*)d_in[19];
    const float* lwhh = (const float*)d_in[20];
    const float* lbih = (const float*)d_in[21];
    const float* lbhh = (const float*)d_in[22];
    const float* Wp1  = (const float*)d_in[23];
    const float* bp1  = (const float*)d_in[24];
    const float* Wp2  = (const float*)d_in[25];
    const float* bp2  = (const float*)d_in[26];

    float* ws = (float*)d_ws;
    float* h    = ws; ws += (size_t)NV * DD;
    float* h0   = ws; ws += (size_t)NV * DD;
    float* e_h  = ws; ws += (size_t)NE * DD;
    float* t3   = ws; ws += (size_t)NE * 64 * NDEPTH;
    float* agg  = ws; ws += (size_t)NV * DD;
    float* attbuf = ws; ws += NV;
    int* deg     = (int*)ws; ws += NV;
    int* cur     = (int*)ws; ws += NV;
    int* estart  = (int*)ws; ws += (NV + 1);
    int* esorted = (int*)ws; ws += NE;
    int* gstart  = (int*)ws; ws += (NG + 1);

    // prolog: embeds + graph bounds + deg zero (one launch)
    k_prolog<<<3755 + (NV + 255) / 256, 256, 0, stream>>>(node, Wn, bn, h, h0,
                                                          edge, We, be, e_h,
                                                          n2g, gstart, deg);
    // all three layers' t + src histogram + agg zero (one launch)
    k_edge_t3<<<NDEPTH * (NE / EPB) + (NE + 255) / 256, 256, 0, stream>>>(
        e_h, eW1, eb1, t3, agg, src, deg);
    k_scan<<<1, SCAN_T, 0, stream>>>(deg, estart, cur);
    k_scatter<<<(NE + 255) / 256, 256, 0, stream>>>(src, cur, esorted);

    for (int l = 0; l < NDEPTH; ++l) {
        k_fused<<<NV / NBK, 1024, 0, stream>>>(h, eW2 + (size_t)l * 64 * 1024, eb2 + l * 1024,
                                               t3 + (size_t)l * NE * 64, dst, estart, esorted, agg);
        k_gru_ln<<<NV / 8, 256, 0, stream>>>(agg, h0,
                                             gwih + (size_t)l * 96 * DD, gwhh + (size_t)l * 96 * DD,
                                             gbih + l * 96, gbhh + l * 96,
                                             lng + l * DD, lnb + l * DD, h);
    }

    k_s2s<<<NG, 256, 0, stream>>>(h, gstart, lwih, lwhh, lbih, lbhh, Wp1, bp1, Wp2, bp2,
                                  attbuf, (float*)d_out);
}

// Round 14
// 519.868 us; speedup vs baseline: 1.7201x; 1.0922x over previous
//
#include <hip/hip_runtime.h>
#include <math.h>

#define NV 20000
#define NE 100000
#define DD 32
#define NG 1000
#define NDEPTH 3
#define S2S 6
#define NBK 8    // src-nodes per block in k_fused
#define EPB 32   // edges per block in k_edge_t3
#define CAPN 128 // max nodes of one graph staged in LDS
#define SCAN_T 256
#define SCAN_C 80  // 256*80 = 20480 >= NV

__device__ __forceinline__ float sigmoidf_(float x) { return 1.0f / (1.0f + __expf(-x)); }

// ---------------- prolog: embed_node | embed_edge | graph bounds | deg zero ----------------
__global__ void k_prolog(const float* __restrict__ node, const float* __restrict__ Wn,
                         const float* __restrict__ bn, float* __restrict__ h,
                         float* __restrict__ h0,
                         const float* __restrict__ edge, const float* __restrict__ We,
                         const float* __restrict__ be, float* __restrict__ e_h,
                         const int* __restrict__ n2g, int* __restrict__ gstart,
                         int* __restrict__ deg) {
    __shared__ float sWn[36 * DD];
    __shared__ float sbn[DD];
    __shared__ float sxn[32][36];
    __shared__ float sWe[12 * DD];
    __shared__ float sbe[DD];
    __shared__ float sxe[32][12];
    int tid = threadIdx.x;
    int b = blockIdx.x;
    if (b < 625) {
        for (int i = tid; i < 36 * DD; i += 256) sWn[i] = Wn[i];
        if (tid < DD) sbn[tid] = bn[tid];
        int v0 = b * 32;
        for (int i = tid; i < 32 * 36; i += 256) sxn[i / 36][i % 36] = node[(size_t)v0 * 36 + i];
        __syncthreads();
        int f = tid & 31;
        int nb = tid >> 5;
        for (int g = 0; g < 4; ++g) {
            int n = nb + 8 * g;
            float acc = sbn[f];
            #pragma unroll
            for (int i = 0; i < 36; ++i) acc += sxn[n][i] * sWn[i * DD + f];
            float y = acc > 0.f ? acc : 0.01f * acc;
            h[(size_t)(v0 + n) * DD + f] = y;
            h0[(size_t)(v0 + n) * DD + f] = y;
        }
    } else if (b < 3750) {
        for (int i = tid; i < 12 * DD; i += 256) sWe[i] = We[i];
        if (tid < DD) sbe[tid] = be[tid];
        int e0 = (b - 625) * 32;
        for (int i = tid; i < 32 * 12; i += 256) sxe[i / 12][i % 12] = edge[(size_t)e0 * 12 + i];
        __syncthreads();
        int f = tid & 31;
        int nb = tid >> 5;
        for (int g = 0; g < 4; ++g) {
            int n = nb + 8 * g;
            float acc = sbe[f];
            #pragma unroll
            for (int i = 0; i < 12; ++i) acc += sxe[n][i] * sWe[i * DD + f];
            float y = acc > 0.f ? acc : 0.01f * acc;
            e_h[(size_t)(e0 + n) * DD + f] = y;
        }
    } else if (b < 3755) {
        int g = (b - 3750) * 256 + tid;
        if (g <= NG) {
            int lo = 0, hi = NV;
            while (lo < hi) {
                int mid = (lo + hi) >> 1;
                if (n2g[mid] < g) lo = mid + 1; else hi = mid;
            }
            gstart[g] = lo;
        }
    } else {
        int i = (b - 3755) * 256 + tid;
        if (i < NV) deg[i] = 0;
    }
}

// ---------------- CSR build ----------------
__global__ void k_scan(const int* __restrict__ deg, int* __restrict__ estart, int* __restrict__ cur) {
    __shared__ int sdeg[SCAN_T * SCAN_C];
    __shared__ int spart[SCAN_T];
    int tid = threadIdx.x;
    for (int i = tid; i < SCAN_T * SCAN_C; i += SCAN_T) sdeg[i] = (i < NV) ? deg[i] : 0;
    __syncthreads();
    int base = tid * SCAN_C;
    int sum = 0;
    for (int j = 0; j < SCAN_C; ++j) sum += sdeg[base + j];
    spart[tid] = sum;
    __syncthreads();
    for (int off = 1; off < SCAN_T; off <<= 1) {
        int v = (tid >= off) ? spart[tid - off] : 0;
        __syncthreads();
        spart[tid] += v;
        __syncthreads();
    }
    int run = spart[tid] - sum;
    for (int j = 0; j < SCAN_C; ++j) {
        int idx = base + j;
        if (idx < NV) { estart[idx] = run; cur[idx] = run; }
        run += sdeg[base + j];
    }
    if (tid == SCAN_T - 1) estart[NV] = run;
}

// scatter by src; packs local node index (s & 7) in bits 28..30
__global__ void k_scatter(const int* __restrict__ src, int* __restrict__ cur,
                          int* __restrict__ esorted) {
    int e = blockIdx.x * blockDim.x + threadIdx.x;
    if (e < NE) {
        int s = src[e];
        int pos = atomicAdd(&cur[s], 1);
        esorted[pos] = e | ((s & (NBK - 1)) << 28);
    }
}

// ---------------- all-layer edge hidden + src histogram ----------------
// blocks [0, 3*(NE/EPB)): t[l] = relu(e_h @ eW1[l] + eb1[l]); first 2500 also zero agg.
// blocks [3*(NE/EPB), +391): histogram of src into deg.
__global__ void k_edge_t3(const float* __restrict__ e_h, const float* __restrict__ eW1,
                          const float* __restrict__ eb1, float* __restrict__ t3,
                          float* __restrict__ agg,
                          const int* __restrict__ src, int* __restrict__ deg) {
    __shared__ float sW[DD * 64];
    __shared__ float sb[64];
    int tid = threadIdx.x;
    int b = blockIdx.x;
    if (b >= NDEPTH * (NE / EPB)) {
        int e = (b - NDEPTH * (NE / EPB)) * 256 + tid;
        if (e < NE) atomicAdd(&deg[src[e]], 1);
        return;
    }
    if (b < (NV * DD) / 256) agg[(size_t)b * 256 + tid] = 0.f;
    int l = b / (NE / EPB), bb = b % (NE / EPB);
    const float* W = eW1 + (size_t)l * DD * 64;
    float* t = t3 + (size_t)l * NE * 64;
    for (int i = tid; i < DD * 64; i += 256) sW[i] = W[i];
    if (tid < 64) sb[tid] = eb1[l * 64 + tid];
    int e0 = bb * EPB;
    __syncthreads();
    int k = tid & 63;
    int nb = tid >> 6;
    float acc[8];
    #pragma unroll
    for (int g = 0; g < 8; ++g) acc[g] = sb[k];
    #pragma unroll
    for (int d4 = 0; d4 < 8; ++d4) {
        float4 ex[8];
        #pragma unroll
        for (int g = 0; g < 8; ++g)
            ex[g] = *(const float4*)(e_h + (size_t)(e0 + nb + 4 * g) * DD + d4 * 4);
        #pragma unroll
        for (int dd = 0; dd < 4; ++dd) {
            float w = sW[(d4 * 4 + dd) * 64 + k];
            #pragma unroll
            for (int g = 0; g < 8; ++g)
                acc[g] = fmaf((&ex[g].x)[dd], w, acc[g]);
        }
    }
    #pragma unroll
    for (int g = 0; g < 8; ++g)
        t[(size_t)(e0 + nb + 4 * g) * 64 + k] = fmaxf(acc[g], 0.f);
}

// ---------------- fused: per-tile A in LDS + chunked balanced edge phase ----------------
// 1024 threads: phase-1 (kb 0..31, f 0..31), k = kb + 32*jj; phase-2: 16 waves split the
// block's whole edge range into equal contiguous chunks; Areg reloaded only on node change.
__global__ __launch_bounds__(1024, 8) void k_fused(const float* __restrict__ h,
        const float* __restrict__ eW2, const float* __restrict__ eb2,
        const float* __restrict__ t, const int* __restrict__ dst,
        const int* __restrict__ estart, const int* __restrict__ esorted,
        float* __restrict__ agg) {
    int v0 = blockIdx.x * NBK;
    __shared__ float sA[NBK][64][32];   // 64 KB, [n][k][f]
    __shared__ float sbb[NBK][32];
    int tid = threadIdx.x;
    int lane = tid & 63;

    // wave-register h tile: lane l holds h[v0 + (l>>3)][4*(l&7) .. +3] (every wave)
    float4 hv4 = *(const float4*)(h + (size_t)(v0 + (lane >> 3)) * DD + 4 * (lane & 7));
    float ha[4] = {hv4.x, hv4.y, hv4.z, hv4.w};

    int f = tid & 31;
    int kb = tid >> 5;                  // 0..31
    const float* wbase = eW2 + kb * 1024 + f;

    float acc[2][8];
    #pragma unroll
    for (int jj = 0; jj < 2; ++jj)
        #pragma unroll
        for (int n = 0; n < 8; ++n) acc[jj][n] = 0.f;

    #pragma unroll
    for (int d4 = 0; d4 < 8; ++d4) {
        float hs[8][4];
        #pragma unroll
        for (int n = 0; n < 8; ++n)
            #pragma unroll
            for (int dd = 0; dd < 4; ++dd)
                hs[n][dd] = __builtin_bit_cast(float,
                    __builtin_amdgcn_readlane(__builtin_bit_cast(int, ha[dd]), n * 8 + d4));
        #pragma unroll
        for (int jj = 0; jj < 2; ++jj) {
            const float* wp = wbase + jj * 32 * 1024 + d4 * 4 * 32;
            #pragma unroll
            for (int dd = 0; dd < 4; ++dd) {
                float w = wp[dd * 32];
                #pragma unroll
                for (int n = 0; n < 8; ++n) acc[jj][n] = fmaf(hs[n][dd], w, acc[jj][n]);
            }
        }
    }
    #pragma unroll
    for (int jj = 0; jj < 2; ++jj)
        #pragma unroll
        for (int n = 0; n < 8; ++n)
            sA[n][kb + 32 * jj][f] = acc[jj][n];

    if (tid < 256) {
        int n = tid >> 5;
        float bacc = 0.f;
        #pragma unroll
        for (int d = 0; d < DD; ++d) {
            float hvv = __shfl(ha[d & 3], n * 8 + (d >> 2), 64);
            bacc = fmaf(hvv, eb2[d * 32 + f], bacc);
        }
        sbb[n][f] = bacc;
    }
    __syncthreads();

    // edge phase: balanced contiguous chunks over the block's edge range.
    int w = tid >> 6;                   // wave 0..15
    int hf = lane >> 5;
    int e0b = estart[v0], e1b = estart[v0 + NBK];
    int total = e1b - e0b;
    int chunk = (total + 15) >> 4;
    int is = e0b + w * chunk;
    int ie = is + chunk; if (ie > e1b) ie = e1b;
    float Areg[32];
    float bbv = 0.f;
    int curn = -1;
    if (is < ie) {
        int pk = esorted[is];
        int e = pk & 0xFFFFFF, ls = pk >> 28;
        float tv = t[(size_t)e * 64 + lane];
        int dn = dst[e];
        int i = is;
        while (i < ie) {
            ++i;
            float tv2 = 0.f; int dn2 = 0, ls2 = 0;
            if (i < ie) {
                int pk2 = esorted[i];
                int e2 = pk2 & 0xFFFFFF; ls2 = pk2 >> 28;
                tv2 = t[(size_t)e2 * 64 + lane];
                dn2 = dst[e2];
            }
            if (ls != curn) {           // wave-uniform branch; reload on node change only
                curn = ls;
                #pragma unroll
                for (int q = 0; q < 32; ++q)
                    Areg[q] = sA[ls][2 * q + hf][f];
                bbv = sbb[ls][f];
            }
            float m0 = 0.f, m1 = 0.f, m2 = 0.f, m3 = 0.f;
            #pragma unroll
            for (int q = 0; q < 32; q += 4) {
                m0 = fmaf(__shfl(tv, 2 * q + hf, 64),       Areg[q],     m0);
                m1 = fmaf(__shfl(tv, 2 * (q + 1) + hf, 64), Areg[q + 1], m1);
                m2 = fmaf(__shfl(tv, 2 * (q + 2) + hf, 64), Areg[q + 2], m2);
                m3 = fmaf(__shfl(tv, 2 * (q + 3) + hf, 64), Areg[q + 3], m3);
            }
            float m = (m0 + m1) + (m2 + m3);
            m += __shfl_xor(m, 32, 64);
            if (lane < 32) atomicAdd(&agg[(size_t)dn * DD + f], m + bbv);
            tv = tv2; dn = dn2; ls = ls2;
        }
    }
}

// ---------------- GRU + LayerNorm (8 nodes/block); re-zeroes agg for next layer ----------------
__global__ __launch_bounds__(256, 2) void k_gru_ln(float* __restrict__ agg,
                         const float* __restrict__ h0,
                         const float* __restrict__ wih, const float* __restrict__ whh,
                         const float* __restrict__ bih, const float* __restrict__ bhh,
                         const float* __restrict__ lng, const float* __restrict__ lnb,
                         float* __restrict__ h) {
    __shared__ float sWT[2][3][32][33];   // [ih/hh][gate][f][j], j-dim padded
    __shared__ float sbih[96], sbhh[96], sg[DD], sb[DD];
    int tid = threadIdx.x;
    for (int i = tid; i < 3072; i += 256) {
        int g = i >> 10, j = (i >> 5) & 31, f = i & 31;
        sWT[0][g][f][j] = wih[i];
        sWT[1][g][f][j] = whh[i];
    }
    if (tid < 96) { sbih[tid] = bih[tid]; sbhh[tid] = bhh[tid]; }
    if (tid < DD) { sg[tid] = lng[tid]; sb[tid] = lnb[tid]; }
    int v0 = blockIdx.x * 8;
    __syncthreads();
    int j = tid & 31;
    int n = v0 + (tid >> 5);
    float4 aq[8], hq[8];
    #pragma unroll
    for (int f4 = 0; f4 < 8; ++f4) {
        float4 a = *(const float4*)(agg + (size_t)n * DD + f4 * 4);
        a.x = fmaxf(a.x, 0.f); a.y = fmaxf(a.y, 0.f); a.z = fmaxf(a.z, 0.f); a.w = fmaxf(a.w, 0.f);
        aq[f4] = a;
        hq[f4] = *(const float4*)(h0 + (size_t)n * DD + f4 * 4);
    }
    agg[(size_t)n * DD + j] = 0.f;   // ready for next layer's atomics
    float h0j = h0[(size_t)n * DD + j];
    float gi0 = 0.f, gi1 = 0.f, gi2 = 0.f, gh0 = 0.f, gh1 = 0.f, gh2 = 0.f;
    #pragma unroll
    for (int f4 = 0; f4 < 8; ++f4) {
        #pragma unroll
        for (int dd = 0; dd < 4; ++dd) {
            int f = f4 * 4 + dd;
            float a = (&aq[f4].x)[dd], hh = (&hq[f4].x)[dd];
            gi0 = fmaf(a, sWT[0][0][f][j], gi0);
            gi1 = fmaf(a, sWT[0][1][f][j], gi1);
            gi2 = fmaf(a, sWT[0][2][f][j], gi2);
            gh0 = fmaf(hh, sWT[1][0][f][j], gh0);
            gh1 = fmaf(hh, sWT[1][1][f][j], gh1);
            gh2 = fmaf(hh, sWT[1][2][f][j], gh2);
        }
    }
    float r = sigmoidf_(gi0 + sbih[j] + gh0 + sbhh[j]);
    float z = sigmoidf_(gi1 + sbih[DD + j] + gh1 + sbhh[DD + j]);
    float nn = tanhf(gi2 + sbih[2 * DD + j] + r * (gh2 + sbhh[2 * DD + j]));
    float hnew = (1.f - z) * nn + z * h0j;
    float mu = hnew;
    #pragma unroll
    for (int o = 16; o; o >>= 1) mu += __shfl_xor(mu, o, 64);
    mu *= (1.f / DD);
    float d = hnew - mu;
    float var = d * d;
    #pragma unroll
    for (int o = 16; o; o >>= 1) var += __shfl_xor(var, o, 64);
    var *= (1.f / DD);
    float inv = rsqrtf(var + 1e-5f);
    h[(size_t)n * DD + j] = d * inv * sg[j] + sb[j];
}

// ---------------- fused Set2Set + prediction MLP: 256 threads per graph ----------------
__global__ __launch_bounds__(256) void k_s2s(const float* __restrict__ h,
                      const int* __restrict__ gstart,
                      const float* __restrict__ wih, const float* __restrict__ whh,
                      const float* __restrict__ bih, const float* __restrict__ bhh,
                      const float* __restrict__ Wp1, const float* __restrict__ bp1,
                      const float* __restrict__ Wp2, const float* __restrict__ bp2,
                      float* __restrict__ attbuf, float* __restrict__ out) {
    int g = blockIdx.x, tid = threadIdx.x;
    int s = gstart[g], e = gstart[g + 1], cnt = e - s;
    bool inlds = (cnt <= CAPN);
    __shared__ float sh[CAPN * 33];
    __shared__ float qs[64], shh[32], scc[32], gbuf[128];
    __shared__ float satt[256];
    __shared__ float red[4];
    __shared__ float rpart[8][32];
    if (inlds) {
        for (int idx = tid; idx < cnt * 32; idx += 256) {
            int v = idx >> 5, f = idx & 31;
            sh[v * 33 + f] = h[(size_t)(s + v) * 32 + f];
        }
    }
    if (tid < 64) qs[tid] = 0.f;
    if (tid < 32) { shh[tid] = 0.f; scc[tid] = 0.f; }
    __syncthreads();
    for (int it = 0; it < S2S; ++it) {
        if (tid < 128) {
            float gv = bih[tid] + bhh[tid];
            const float4* w4 = (const float4*)(wih + tid * 64);
            #pragma unroll
            for (int i = 0; i < 16; ++i) {
                float4 w = w4[i];
                gv += qs[4 * i] * w.x + qs[4 * i + 1] * w.y + qs[4 * i + 2] * w.z + qs[4 * i + 3] * w.w;
            }
            const float4* u4 = (const float4*)(whh + tid * 32);
            #pragma unroll
            for (int i = 0; i < 8; ++i) {
                float4 w = u4[i];
                gv += shh[4 * i] * w.x + shh[4 * i + 1] * w.y + shh[4 * i + 2] * w.z + shh[4 * i + 3] * w.w;
            }
            gbuf[tid] = gv;
        }
        __syncthreads();
        if (tid < 32) {
            float ii = gbuf[tid], ff = gbuf[32 + tid], gg = gbuf[64 + tid], oo = gbuf[96 + tid];
            float c = sigmoidf_(ff) * scc[tid] + sigmoidf_(ii) * tanhf(gg);
            scc[tid] = c;
            float hv = sigmoidf_(oo) * tanhf(c);
            shh[tid] = hv;
            qs[tid] = hv;
        }
        __syncthreads();
        float pmax = -1e30f;
        if (inlds) {
            float a = -1e30f;
            if (tid < cnt) {
                float acc = 0.f;
                #pragma unroll
                for (int f = 0; f < 32; ++f) acc += sh[tid * 33 + f] * shh[f];
                a = acc;
            }
            satt[tid] = a;
            pmax = a;
        } else {
            for (int v = tid; v < cnt; v += 256) {
                float acc = 0.f;
                const float* hp = h + (size_t)(s + v) * 32;
                #pragma unroll
                for (int f = 0; f < 32; ++f) acc += hp[f] * shh[f];
                attbuf[s + v] = acc;
                pmax = fmaxf(pmax, acc);
            }
        }
        #pragma unroll
        for (int o = 32; o; o >>= 1) pmax = fmaxf(pmax, __shfl_xor(pmax, o, 64));
        if ((tid & 63) == 0) red[tid >> 6] = pmax;
        __syncthreads();
        float m = fmaxf(fmaxf(red[0], red[1]), fmaxf(red[2], red[3]));
        float psum = 0.f;
        if (inlds) {
            if (tid < cnt) { float exv = __expf(satt[tid] - m); satt[tid] = exv; psum = exv; }
        } else {
            for (int v = tid; v < cnt; v += 256) {
                float exv = __expf(attbuf[s + v] - m); attbuf[s + v] = exv; psum += exv;
            }
        }
        #pragma unroll
        for (int o = 32; o; o >>= 1) psum += __shfl_xor(psum, o, 64);
        __syncthreads();
        if ((tid & 63) == 0) red[tid >> 6] = psum;
        __syncthreads();
        float denom = red[0] + red[1] + red[2] + red[3];
        int f = tid & 31, vc = tid >> 5;
        float racc = 0.f;
        if (inlds) {
            for (int v = vc; v < cnt; v += 8) racc += satt[v] * sh[v * 33 + f];
        } else {
            for (int v = vc; v < cnt; v += 8) racc += attbuf[s + v] * h[(size_t)(s + v) * 32 + f];
        }
        rpart[vc][f] = racc;
        __syncthreads();
        if (tid < 32) {
            float r = 0.f;
            #pragma unroll
            for (int c2 = 0; c2 < 8; ++c2) r += rpart[c2][tid];
            qs[32 + tid] = (cnt > 0) ? (r / denom) : 0.f;
        }
        __syncthreads();
    }
    if (tid < 32) {
        float u = bp1[tid];
        #pragma unroll
        for (int p = 0; p < 64; ++p) u += qs[p] * Wp1[p * 32 + tid];
        u = fmaxf(u, 0.f);
        float pr = u * Wp2[tid];
        #pragma unroll
        for (int o = 16; o; o >>= 1) pr += __shfl_xor(pr, o, 64);
        if (tid == 0) out[g] = pr + bp2[0];
    }
}

extern "C" void kernel_launch(void* const* d_in, const int* in_sizes, int n_in,
                              void* d_out, int out_size, void* d_ws, size_t ws_size,
                              hipStream_t stream) {
    const float* node = (const float*)d_in[0];
    const float* edge = (const float*)d_in[1];
    const int*   src  = (const int*)d_in[2];
    const int*   dst  = (const int*)d_in[3];
    const int*   n2g  = (const int*)d_in[4];
    const float* Wn   = (const float*)d_in[5];
    const float* bn   = (const float*)d_in[6];
    const float* We   = (const float*)d_in[7];
    const float* be   = (const float*)d_in[8];
    const float* eW1  = (const float*)d_in[9];
    const float* eb1  = (const float*)d_in[10];
    const float* eW2  = (const float*)d_in[11];
    const float* eb2  = (const float*)d_in[12];
    const float* gwih = (const float*)d_in[13];
    const float* gwhh = (const float*)d_in[14];
    const float* gbih = (const float*)d_in[15];
    const float* gbhh = (const float*)d_in[16];
    const float* lng  = (const float*)d_in[17];
    const float* lnb  = (const float*)d_in[18];
    const float* lwih = (const float*)d_in[19];
    const float* lwhh = (const float*)d_in[20];
    const float* lbih = (const float*)d_in[21];
    const float* lbhh = (const float*)d_in[22];
    const float* Wp1  = (const float*)d_in[23];
    const float* bp1  = (const float*)d_in[24];
    const float* Wp2  = (const float*)d_in[25];
    const float* bp2  = (const float*)d_in[26];

    float* ws = (float*)d_ws;
    float* h    = ws; ws += (size_t)NV * DD;
    float* h0   = ws; ws += (size_t)NV * DD;
    float* e_h  = ws; ws += (size_t)NE * DD;
    float* t3   = ws; ws += (size_t)NE * 64 * NDEPTH;
    float* agg  = ws; ws += (size_t)NV * DD;
    float* attbuf = ws; ws += NV;
    int* deg     = (int*)ws; ws += NV;
    int* cur     = (int*)ws; ws += NV;
    int* estart  = (int*)ws; ws += (NV + 1);
    int* esorted = (int*)ws; ws += NE;
    int* gstart  = (int*)ws; ws += (NG + 1);

    // prolog: embeds + graph bounds + deg zero (one launch)
    k_prolog<<<3755 + (NV + 255) / 256, 256, 0, stream>>>(node, Wn, bn, h, h0,
                                                          edge, We, be, e_h,
                                                          n2g, gstart, deg);
    // all three layers' t + src histogram + agg zero (one launch)
    k_edge_t3<<<NDEPTH * (NE / EPB) + (NE + 255) / 256, 256, 0, stream>>>(
        e_h, eW1, eb1, t3, agg, src, deg);
    k_scan<<<1, SCAN_T, 0, stream>>>(deg, estart, cur);
    k_scatter<<<(NE + 255) / 256, 256, 0, stream>>>(src, cur, esorted);

    for (int l = 0; l < NDEPTH; ++l) {
        k_fused<<<NV / NBK, 1024, 0, stream>>>(h, eW2 + (size_t)l * 64 * 1024, eb2 + l * 1024,
                                               t3 + (size_t)l * NE * 64, dst, estart, esorted, agg);
        k_gru_ln<<<NV / 8, 256, 0, stream>>>(agg, h0,
                                             gwih + (size_t)l * 96 * DD, gwhh + (size_t)l * 96 * DD,
                                             gbih + l * 96, gbhh + l * 96,
                                             lng + l * DD, lnb + l * DD, h);
    }

    k_s2s<<<NG, 256, 0, stream>>>(h, gstart, lwih, lwhh, lbih, lbhh, Wp1, bp1, Wp2, bp2,
                                  attbuf, (float*)d_out);
}

// Round 15
// 518.998 us; speedup vs baseline: 1.7230x; 1.0017x over previous
//
#include <hip/hip_runtime.h>
#include <math.h>

#define NV 20000
#define NE 100000
#define DD 32
#define NG 1000
#define NDEPTH 3
#define S2S 6
#define NBK 8    // src-nodes per block in k_fused
#define EPB 32   // edges per block in k_edge_t3
#define CAPN 128 // max nodes of one graph staged in LDS
#define SCAN_T 256
#define SCAN_C 80  // 256*80 = 20480 >= NV

__device__ __forceinline__ float sigmoidf_(float x) { return 1.0f / (1.0f + __expf(-x)); }

// ---------------- prolog: embed_node | embed_edge | graph bounds | deg zero ----------------
__global__ void k_prolog(const float* __restrict__ node, const float* __restrict__ Wn,
                         const float* __restrict__ bn, float* __restrict__ h,
                         float* __restrict__ h0,
                         const float* __restrict__ edge, const float* __restrict__ We,
                         const float* __restrict__ be, float* __restrict__ e_h,
                         const int* __restrict__ n2g, int* __restrict__ gstart,
                         int* __restrict__ deg) {
    __shared__ float sWn[36 * DD];
    __shared__ float sbn[DD];
    __shared__ float sxn[32][36];
    __shared__ float sWe[12 * DD];
    __shared__ float sbe[DD];
    __shared__ float sxe[32][12];
    int tid = threadIdx.x;
    int b = blockIdx.x;
    if (b < 625) {
        for (int i = tid; i < 36 * DD; i += 256) sWn[i] = Wn[i];
        if (tid < DD) sbn[tid] = bn[tid];
        int v0 = b * 32;
        for (int i = tid; i < 32 * 36; i += 256) sxn[i / 36][i % 36] = node[(size_t)v0 * 36 + i];
        __syncthreads();
        int f = tid & 31;
        int nb = tid >> 5;
        for (int g = 0; g < 4; ++g) {
            int n = nb + 8 * g;
            float acc = sbn[f];
            #pragma unroll
            for (int i = 0; i < 36; ++i) acc += sxn[n][i] * sWn[i * DD + f];
            float y = acc > 0.f ? acc : 0.01f * acc;
            h[(size_t)(v0 + n) * DD + f] = y;
            h0[(size_t)(v0 + n) * DD + f] = y;
        }
    } else if (b < 3750) {
        for (int i = tid; i < 12 * DD; i += 256) sWe[i] = We[i];
        if (tid < DD) sbe[tid] = be[tid];
        int e0 = (b - 625) * 32;
        for (int i = tid; i < 32 * 12; i += 256) sxe[i / 12][i % 12] = edge[(size_t)e0 * 12 + i];
        __syncthreads();
        int f = tid & 31;
        int nb = tid >> 5;
        for (int g = 0; g < 4; ++g) {
            int n = nb + 8 * g;
            float acc = sbe[f];
            #pragma unroll
            for (int i = 0; i < 12; ++i) acc += sxe[n][i] * sWe[i * DD + f];
            float y = acc > 0.f ? acc : 0.01f * acc;
            e_h[(size_t)(e0 + n) * DD + f] = y;
        }
    } else if (b < 3755) {
        int g = (b - 3750) * 256 + tid;
        if (g <= NG) {
            int lo = 0, hi = NV;
            while (lo < hi) {
                int mid = (lo + hi) >> 1;
                if (n2g[mid] < g) lo = mid + 1; else hi = mid;
            }
            gstart[g] = lo;
        }
    } else {
        int i = (b - 3755) * 256 + tid;
        if (i < NV) deg[i] = 0;
    }
}

// ---------------- CSR build ----------------
__global__ void k_scan(const int* __restrict__ deg, int* __restrict__ estart, int* __restrict__ cur) {
    __shared__ int sdeg[SCAN_T * SCAN_C];
    __shared__ int spart[SCAN_T];
    int tid = threadIdx.x;
    for (int i = tid; i < SCAN_T * SCAN_C; i += SCAN_T) sdeg[i] = (i < NV) ? deg[i] : 0;
    __syncthreads();
    int base = tid * SCAN_C;
    int sum = 0;
    for (int j = 0; j < SCAN_C; ++j) sum += sdeg[base + j];
    spart[tid] = sum;
    __syncthreads();
    for (int off = 1; off < SCAN_T; off <<= 1) {
        int v = (tid >= off) ? spart[tid - off] : 0;
        __syncthreads();
        spart[tid] += v;
        __syncthreads();
    }
    int run = spart[tid] - sum;
    for (int j = 0; j < SCAN_C; ++j) {
        int idx = base + j;
        if (idx < NV) { estart[idx] = run; cur[idx] = run; }
        run += sdeg[base + j];
    }
    if (tid == SCAN_T - 1) estart[NV] = run;
}

// scatter by src; packs local node index (s & 7) in bits 28..30
__global__ void k_scatter(const int* __restrict__ src, int* __restrict__ cur,
                          int* __restrict__ esorted) {
    int e = blockIdx.x * blockDim.x + threadIdx.x;
    if (e < NE) {
        int s = src[e];
        int pos = atomicAdd(&cur[s], 1);
        esorted[pos] = e | ((s & (NBK - 1)) << 28);
    }
}

// ---------------- all-layer edge hidden + src histogram ----------------
__global__ void k_edge_t3(const float* __restrict__ e_h, const float* __restrict__ eW1,
                          const float* __restrict__ eb1, float* __restrict__ t3,
                          float* __restrict__ agg,
                          const int* __restrict__ src, int* __restrict__ deg) {
    __shared__ float sW[DD * 64];
    __shared__ float sb[64];
    int tid = threadIdx.x;
    int b = blockIdx.x;
    if (b >= NDEPTH * (NE / EPB)) {
        int e = (b - NDEPTH * (NE / EPB)) * 256 + tid;
        if (e < NE) atomicAdd(&deg[src[e]], 1);
        return;
    }
    if (b < (NV * DD) / 256) agg[(size_t)b * 256 + tid] = 0.f;
    int l = b / (NE / EPB), bb = b % (NE / EPB);
    const float* W = eW1 + (size_t)l * DD * 64;
    float* t = t3 + (size_t)l * NE * 64;
    for (int i = tid; i < DD * 64; i += 256) sW[i] = W[i];
    if (tid < 64) sb[tid] = eb1[l * 64 + tid];
    int e0 = bb * EPB;
    __syncthreads();
    int k = tid & 63;
    int nb = tid >> 6;
    float acc[8];
    #pragma unroll
    for (int g = 0; g < 8; ++g) acc[g] = sb[k];
    #pragma unroll
    for (int d4 = 0; d4 < 8; ++d4) {
        float4 ex[8];
        #pragma unroll
        for (int g = 0; g < 8; ++g)
            ex[g] = *(const float4*)(e_h + (size_t)(e0 + nb + 4 * g) * DD + d4 * 4);
        #pragma unroll
        for (int dd = 0; dd < 4; ++dd) {
            float w = sW[(d4 * 4 + dd) * 64 + k];
            #pragma unroll
            for (int g = 0; g < 8; ++g)
                acc[g] = fmaf((&ex[g].x)[dd], w, acc[g]);
        }
    }
    #pragma unroll
    for (int g = 0; g < 8; ++g)
        t[(size_t)(e0 + nb + 4 * g) * 64 + k] = fmaxf(acc[g], 0.f);
}

// ---------------- fused: per-tile A in LDS + chunked balanced edge phase ----------------
// sA layout [n][f][k] (k padded to 66): phase-2 Areg reload = 16x ds_read_b64;
// k-mapping k = 32*hf + q; bpermute sel 32*hf+q (base hf<<7 hoisted, 4q folds to offset).
__global__ __launch_bounds__(1024, 8) void k_fused(const float* __restrict__ h,
        const float* __restrict__ eW2, const float* __restrict__ eb2,
        const float* __restrict__ t, const int* __restrict__ dst,
        const int* __restrict__ estart, const int* __restrict__ esorted,
        float* __restrict__ agg) {
    int v0 = blockIdx.x * NBK;
    __shared__ float sA[NBK][32][66];   // 67.6 KB, [n][f][k+pad]
    __shared__ float sbb[NBK][32];
    int tid = threadIdx.x;
    int lane = tid & 63;

    // wave-register h tile: lane l holds h[v0 + (l>>3)][4*(l&7) .. +3] (every wave)
    float4 hv4 = *(const float4*)(h + (size_t)(v0 + (lane >> 3)) * DD + 4 * (lane & 7));
    float ha[4] = {hv4.x, hv4.y, hv4.z, hv4.w};

    int f = tid & 31;
    int kb = tid >> 5;                  // 0..31
    const float* wbase = eW2 + kb * 1024 + f;

    float2 acc2[2][4];                  // [jj][n-pair]
    #pragma unroll
    for (int jj = 0; jj < 2; ++jj)
        #pragma unroll
        for (int n2 = 0; n2 < 4; ++n2) { acc2[jj][n2].x = 0.f; acc2[jj][n2].y = 0.f; }

    #pragma unroll
    for (int d4 = 0; d4 < 8; ++d4) {
        float2 hs2[4][4];               // [n-pair][dd]
        #pragma unroll
        for (int n2 = 0; n2 < 4; ++n2)
            #pragma unroll
            for (int dd = 0; dd < 4; ++dd) {
                hs2[n2][dd].x = __builtin_bit_cast(float,
                    __builtin_amdgcn_readlane(__builtin_bit_cast(int, ha[dd]), (2 * n2) * 8 + d4));
                hs2[n2][dd].y = __builtin_bit_cast(float,
                    __builtin_amdgcn_readlane(__builtin_bit_cast(int, ha[dd]), (2 * n2 + 1) * 8 + d4));
            }
        #pragma unroll
        for (int jj = 0; jj < 2; ++jj) {
            const float* wp = wbase + jj * 32 * 1024 + d4 * 128;
            #pragma unroll
            for (int dd = 0; dd < 4; ++dd) {
                float w = wp[dd * 32];
                #pragma unroll
                for (int n2 = 0; n2 < 4; ++n2) {
                    acc2[jj][n2].x = fmaf(hs2[n2][dd].x, w, acc2[jj][n2].x);
                    acc2[jj][n2].y = fmaf(hs2[n2][dd].y, w, acc2[jj][n2].y);
                }
            }
        }
    }
    #pragma unroll
    for (int jj = 0; jj < 2; ++jj) {
        int k = kb + 32 * jj;
        #pragma unroll
        for (int n2 = 0; n2 < 4; ++n2) {
            sA[2 * n2][f][k] = acc2[jj][n2].x;
            sA[2 * n2 + 1][f][k] = acc2[jj][n2].y;
        }
    }

    if (tid < 256) {
        int n = tid >> 5;
        const float* hp = h + (size_t)(v0 + n) * DD;
        float bacc = 0.f;
        #pragma unroll
        for (int d4 = 0; d4 < 8; ++d4) {
            float4 h4 = *(const float4*)(hp + d4 * 4);
            bacc = fmaf(h4.x, eb2[(d4 * 4 + 0) * 32 + f], bacc);
            bacc = fmaf(h4.y, eb2[(d4 * 4 + 1) * 32 + f], bacc);
            bacc = fmaf(h4.z, eb2[(d4 * 4 + 2) * 32 + f], bacc);
            bacc = fmaf(h4.w, eb2[(d4 * 4 + 3) * 32 + f], bacc);
        }
        sbb[n][f] = bacc;
    }
    __syncthreads();

    // edge phase: balanced contiguous chunks; lane (f,hf) accumulates k in [32hf, 32hf+32)
    int w = tid >> 6;                   // wave 0..15
    int hf = lane >> 5;
    int bofs = hf << 7;                 // bpermute base addr = (32*hf)<<2
    int e0b = estart[v0], e1b = estart[v0 + NBK];
    int total = e1b - e0b;
    int chunk = (total + 15) >> 4;
    int is = e0b + w * chunk;
    int ie = is + chunk; if (ie > e1b) ie = e1b;
    float Areg[32];
    float bbv = 0.f;
    int curn = -1;
    if (is < ie) {
        int pk = esorted[is];
        int e = pk & 0xFFFFFF, ls = pk >> 28;
        float tv = t[(size_t)e * 64 + lane];
        int dn = dst[e];
        int i = is;
        while (i < ie) {
            ++i;
            float tv2 = 0.f; int dn2 = 0, ls2 = 0;
            if (i < ie) {
                int pk2 = esorted[i];
                int e2 = pk2 & 0xFFFFFF; ls2 = pk2 >> 28;
                tv2 = t[(size_t)e2 * 64 + lane];
                dn2 = dst[e2];
            }
            if (ls != curn) {           // wave-uniform; 16x ds_read_b64
                curn = ls;
                const float2* ap = (const float2*)&sA[ls][f][32 * hf];
                #pragma unroll
                for (int q2 = 0; q2 < 16; ++q2) {
                    float2 a2 = ap[q2];
                    Areg[2 * q2] = a2.x;
                    Areg[2 * q2 + 1] = a2.y;
                }
                bbv = sbb[ls][f];
            }
            int tvb = __builtin_bit_cast(int, tv);
            float m0 = 0.f, m1 = 0.f, m2 = 0.f, m3 = 0.f;
            #pragma unroll
            for (int q = 0; q < 32; q += 4) {
                float b0 = __builtin_bit_cast(float, __builtin_amdgcn_ds_bpermute(bofs + 4 * q, tvb));
                float b1 = __builtin_bit_cast(float, __builtin_amdgcn_ds_bpermute(bofs + 4 * (q + 1), tvb));
                float b2 = __builtin_bit_cast(float, __builtin_amdgcn_ds_bpermute(bofs + 4 * (q + 2), tvb));
                float b3 = __builtin_bit_cast(float, __builtin_amdgcn_ds_bpermute(bofs + 4 * (q + 3), tvb));
                m0 = fmaf(b0, Areg[q], m0);
                m1 = fmaf(b1, Areg[q + 1], m1);
                m2 = fmaf(b2, Areg[q + 2], m2);
                m3 = fmaf(b3, Areg[q + 3], m3);
            }
            float m = (m0 + m1) + (m2 + m3);
            m += __shfl_xor(m, 32, 64);
            if (lane < 32) atomicAdd(&agg[(size_t)dn * DD + f], m + bbv);
            tv = tv2; dn = dn2; ls = ls2;
        }
    }
}

// ---------------- GRU + LayerNorm (8 nodes/block); re-zeroes agg for next layer ----------------
__global__ __launch_bounds__(256, 2) void k_gru_ln(float* __restrict__ agg,
                         const float* __restrict__ h0,
                         const float* __restrict__ wih, const float* __restrict__ whh,
                         const float* __restrict__ bih, const float* __restrict__ bhh,
                         const float* __restrict__ lng, const float* __restrict__ lnb,
                         float* __restrict__ h) {
    __shared__ float sWT[2][3][32][33];   // [ih/hh][gate][f][j], j-dim padded
    __shared__ float sbih[96], sbhh[96], sg[DD], sb[DD];
    int tid = threadIdx.x;
    for (int i = tid; i < 3072; i += 256) {
        int g = i >> 10, j = (i >> 5) & 31, f = i & 31;
        sWT[0][g][f][j] = wih[i];
        sWT[1][g][f][j] = whh[i];
    }
    if (tid < 96) { sbih[tid] = bih[tid]; sbhh[tid] = bhh[tid]; }
    if (tid < DD) { sg[tid] = lng[tid]; sb[tid] = lnb[tid]; }
    int v0 = blockIdx.x * 8;
    __syncthreads();
    int j = tid & 31;
    int n = v0 + (tid >> 5);
    float4 aq[8], hq[8];
    #pragma unroll
    for (int f4 = 0; f4 < 8; ++f4) {
        float4 a = *(const float4*)(agg + (size_t)n * DD + f4 * 4);
        a.x = fmaxf(a.x, 0.f); a.y = fmaxf(a.y, 0.f); a.z = fmaxf(a.z, 0.f); a.w = fmaxf(a.w, 0.f);
        aq[f4] = a;
        hq[f4] = *(const float4*)(h0 + (size_t)n * DD + f4 * 4);
    }
    agg[(size_t)n * DD + j] = 0.f;   // ready for next layer's atomics
    float h0j = h0[(size_t)n * DD + j];
    float gi0 = 0.f, gi1 = 0.f, gi2 = 0.f, gh0 = 0.f, gh1 = 0.f, gh2 = 0.f;
    #pragma unroll
    for (int f4 = 0; f4 < 8; ++f4) {
        #pragma unroll
        for (int dd = 0; dd < 4; ++dd) {
            int f = f4 * 4 + dd;
            float a = (&aq[f4].x)[dd], hh = (&hq[f4].x)[dd];
            gi0 = fmaf(a, sWT[0][0][f][j], gi0);
            gi1 = fmaf(a, sWT[0][1][f][j], gi1);
            gi2 = fmaf(a, sWT[0][2][f][j], gi2);
            gh0 = fmaf(hh, sWT[1][0][f][j], gh0);
            gh1 = fmaf(hh, sWT[1][1][f][j], gh1);
            gh2 = fmaf(hh, sWT[1][2][f][j], gh2);
        }
    }
    float r = sigmoidf_(gi0 + sbih[j] + gh0 + sbhh[j]);
    float z = sigmoidf_(gi1 + sbih[DD + j] + gh1 + sbhh[DD + j]);
    float nn = tanhf(gi2 + sbih[2 * DD + j] + r * (gh2 + sbhh[2 * DD + j]));
    float hnew = (1.f - z) * nn + z * h0j;
    float mu = hnew;
    #pragma unroll
    for (int o = 16; o; o >>= 1) mu += __shfl_xor(mu, o, 64);
    mu *= (1.f / DD);
    float d = hnew - mu;
    float var = d * d;
    #pragma unroll
    for (int o = 16; o; o >>= 1) var += __shfl_xor(var, o, 64);
    var *= (1.f / DD);
    float inv = rsqrtf(var + 1e-5f);
    h[(size_t)n * DD + j] = d * inv * sg[j] + sb[j];
}

// ---------------- fused Set2Set + prediction MLP: 256 threads per graph ----------------
__global__ __launch_bounds__(256) void k_s2s(const float* __restrict__ h,
                      const int* __restrict__ gstart,
                      const float* __restrict__ wih, const float* __restrict__ whh,
                      const float* __restrict__ bih, const float* __restrict__ bhh,
                      const float* __restrict__ Wp1, const float* __restrict__ bp1,
                      const float* __restrict__ Wp2, const float* __restrict__ bp2,
                      float* __restrict__ attbuf, float* __restrict__ out) {
    int g = blockIdx.x, tid = threadIdx.x;
    int s = gstart[g], e = gstart[g + 1], cnt = e - s;
    bool inlds = (cnt <= CAPN);
    __shared__ float sh[CAPN * 33];
    __shared__ float qs[64], shh[32], scc[32], gbuf[128];
    __shared__ float satt[256];
    __shared__ float red[4];
    __shared__ float rpart[8][32];
    if (inlds) {
        for (int idx = tid; idx < cnt * 32; idx += 256) {
            int v = idx >> 5, f = idx & 31;
            sh[v * 33 + f] = h[(size_t)(s + v) * 32 + f];
        }
    }
    if (tid < 64) qs[tid] = 0.f;
    if (tid < 32) { shh[tid] = 0.f; scc[tid] = 0.f; }
    __syncthreads();
    for (int it = 0; it < S2S; ++it) {
        if (tid < 128) {
            float gv = bih[tid] + bhh[tid];
            const float4* w4 = (const float4*)(wih + tid * 64);
            #pragma unroll
            for (int i = 0; i < 16; ++i) {
                float4 w = w4[i];
                gv += qs[4 * i] * w.x + qs[4 * i + 1] * w.y + qs[4 * i + 2] * w.z + qs[4 * i + 3] * w.w;
            }
            const float4* u4 = (const float4*)(whh + tid * 32);
            #pragma unroll
            for (int i = 0; i < 8; ++i) {
                float4 w = u4[i];
                gv += shh[4 * i] * w.x + shh[4 * i + 1] * w.y + shh[4 * i + 2] * w.z + shh[4 * i + 3] * w.w;
            }
            gbuf[tid] = gv;
        }
        __syncthreads();
        if (tid < 32) {
            float ii = gbuf[tid], ff = gbuf[32 + tid], gg = gbuf[64 + tid], oo = gbuf[96 + tid];
            float c = sigmoidf_(ff) * scc[tid] + sigmoidf_(ii) * tanhf(gg);
            scc[tid] = c;
            float hv = sigmoidf_(oo) * tanhf(c);
            shh[tid] = hv;
            qs[tid] = hv;
        }
        __syncthreads();
        float pmax = -1e30f;
        if (inlds) {
            float a = -1e30f;
            if (tid < cnt) {
                float acc = 0.f;
                #pragma unroll
                for (int f = 0; f < 32; ++f) acc += sh[tid * 33 + f] * shh[f];
                a = acc;
            }
            satt[tid] = a;
            pmax = a;
        } else {
            for (int v = tid; v < cnt; v += 256) {
                float acc = 0.f;
                const float* hp = h + (size_t)(s + v) * 32;
                #pragma unroll
                for (int f = 0; f < 32; ++f) acc += hp[f] * shh[f];
                attbuf[s + v] = acc;
                pmax = fmaxf(pmax, acc);
            }
        }
        #pragma unroll
        for (int o = 32; o; o >>= 1) pmax = fmaxf(pmax, __shfl_xor(pmax, o, 64));
        if ((tid & 63) == 0) red[tid >> 6] = pmax;
        __syncthreads();
        float m = fmaxf(fmaxf(red[0], red[1]), fmaxf(red[2], red[3]));
        float psum = 0.f;
        if (inlds) {
            if (tid < cnt) { float exv = __expf(satt[tid] - m); satt[tid] = exv; psum = exv; }
        } else {
            for (int v = tid; v < cnt; v += 256) {
                float exv = __expf(attbuf[s + v] - m); attbuf[s + v] = exv; psum += exv;
            }
        }
        #pragma unroll
        for (int o = 32; o; o >>= 1) psum += __shfl_xor(psum, o, 64);
        __syncthreads();
        if ((tid & 63) == 0) red[tid >> 6] = psum;
        __syncthreads();
        float denom = red[0] + red[1] + red[2] + red[3];
        int f = tid & 31, vc = tid >> 5;
        float racc = 0.f;
        if (inlds) {
            for (int v = vc; v < cnt; v += 8) racc += satt[v] * sh[v * 33 + f];
        } else {
            for (int v = vc; v < cnt; v += 8) racc += attbuf[s + v] * h[(size_t)(s + v) * 32 + f];
        }
        rpart[vc][f] = racc;
        __syncthreads();
        if (tid < 32) {
            float r = 0.f;
            #pragma unroll
            for (int c2 = 0; c2 < 8; ++c2) r += rpart[c2][tid];
            qs[32 + tid] = (cnt > 0) ? (r / denom) : 0.f;
        }
        __syncthreads();
    }
    if (tid < 32) {
        float u = bp1[tid];
        #pragma unroll
        for (int p = 0; p < 64; ++p) u += qs[p] * Wp1[p * 32 + tid];
        u = fmaxf(u, 0.f);
        float pr = u * Wp2[tid];
        #pragma unroll
        for (int o = 16; o; o >>= 1) pr += __shfl_xor(pr, o, 64);
        if (tid == 0) out[g] = pr + bp2[0];
    }
}

extern "C" void kernel_launch(void* const* d_in, const int* in_sizes, int n_in,
                              void* d_out, int out_size, void* d_ws, size_t ws_size,
                              hipStream_t stream) {
    const float* node = (const float*)d_in[0];
    const float* edge = (const float*)d_in[1];
    const int*   src  = (const int*)d_in[2];
    const int*   dst  = (const int*)d_in[3];
    const int*   n2g  = (const int*)d_in[4];
    const float* Wn   = (const float*)d_in[5];
    const float* bn   = (const float*)d_in[6];
    const float* We   = (const float*)d_in[7];
    const float* be   = (const float*)d_in[8];
    const float* eW1  = (const float*)d_in[9];
    const float* eb1  = (const float*)d_in[10];
    const float* eW2  = (const float*)d_in[11];
    const float* eb2  = (const float*)d_in[12];
    const float* gwih = (const float*)d_in[13];
    const float* gwhh = (const float*)d_in[14];
    const float* gbih = (const float*)d_in[15];
    const float* gbhh = (const float*)d_in[16];
    const float* lng  = (const float*)d_in[17];
    const float* lnb  = (const float*)d_in[18];
    const float* lwih = (const float*)d_in[19];
    const float* lwhh = (const float*)d_in[20];
    const float* lbih = (const float*)d_in[21];
    const float* lbhh = (const float*)d_in[22];
    const float* Wp1  = (const float*)d_in[23];
    const float* bp1  = (const float*)d_in[24];
    const float* Wp2  = (const float*)d_in[25];
    const float* bp2  = (const float*)d_in[26];

    float* ws = (float*)d_ws;
    float* h    = ws; ws += (size_t)NV * DD;
    float* h0   = ws; ws += (size_t)NV * DD;
    float* e_h  = ws; ws += (size_t)NE * DD;
    float* t3   = ws; ws += (size_t)NE * 64 * NDEPTH;
    float* agg  = ws; ws += (size_t)NV * DD;
    float* attbuf = ws; ws += NV;
    int* deg     = (int*)ws; ws += NV;
    int* cur     = (int*)ws; ws += NV;
    int* estart  = (int*)ws; ws += (NV + 1);
    int* esorted = (int*)ws; ws += NE;
    int* gstart  = (int*)ws; ws += (NG + 1);

    // prolog: embeds + graph bounds + deg zero (one launch)
    k_prolog<<<3755 + (NV + 255) / 256, 256, 0, stream>>>(node, Wn, bn, h, h0,
                                                          edge, We, be, e_h,
                                                          n2g, gstart, deg);
    // all three layers' t + src histogram + agg zero (one launch)
    k_edge_t3<<<NDEPTH * (NE / EPB) + (NE + 255) / 256, 256, 0, stream>>>(
        e_h, eW1, eb1, t3, agg, src, deg);
    k_scan<<<1, SCAN_T, 0, stream>>>(deg, estart, cur);
    k_scatter<<<(NE + 255) / 256, 256, 0, stream>>>(src, cur, esorted);

    for (int l = 0; l < NDEPTH; ++l) {
        k_fused<<<NV / NBK, 1024, 0, stream>>>(h, eW2 + (size_t)l * 64 * 1024, eb2 + l * 1024,
                                               t3 + (size_t)l * NE * 64, dst, estart, esorted, agg);
        k_gru_ln<<<NV / 8, 256, 0, stream>>>(agg, h0,
                                             gwih + (size_t)l * 96 * DD, gwhh + (size_t)l * 96 * DD,
                                             gbih + l * 96, gbhh + l * 96,
                                             lng + l * DD, lnb + l * DD, h);
    }

    k_s2s<<<NG, 256, 0, stream>>>(h, gstart, lwih, lwhh, lbih, lbhh, Wp1, bp1, Wp2, bp2,
                                  attbuf, (float*)d_out);
}